// Round 4
// baseline (474.046 us; speedup 1.0000x reference)
//
#include <hip/hip_runtime.h>

#define DD 128

typedef __bf16 bf16x8 __attribute__((ext_vector_type(8)));
typedef float f32x4 __attribute__((ext_vector_type(4)));

static __device__ __forceinline__ unsigned short f2bf(float f) {
    unsigned int u = __float_as_uint(f);
    u += 0x7FFF + ((u >> 16) & 1);   // round-to-nearest-even
    return (unsigned short)(u >> 16);
}
static __device__ __forceinline__ float bf2f(unsigned short v) {
    return __uint_as_float(((unsigned)v) << 16);
}

// ---------------- fused CSR build (one kernel, manual grid barrier) ----------
// 256 blocks x 1024 threads: co-resident on 256 CUs (<= 2048 thr/CU), so a
// device-scope arrive-and-spin barrier is safe. Counters zeroed by host memset.

static __device__ __forceinline__ void gbar(int* ctr, int target) {
    __syncthreads();
    if (threadIdx.x == 0) {
        __hip_atomic_fetch_add(ctr, 1, __ATOMIC_ACQ_REL, __HIP_MEMORY_SCOPE_AGENT);
        while (__hip_atomic_load(ctr, __ATOMIC_ACQUIRE, __HIP_MEMORY_SCOPE_AGENT) < target)
            __builtin_amdgcn_s_sleep(2);
    }
    __syncthreads();
}

__global__ __launch_bounds__(1024) void k_build(
    const int* __restrict__ ei, int* __restrict__ cnt, int* __restrict__ rp,
    float* __restrict__ dinv, int* __restrict__ bsum, int2* __restrict__ csr,
    int* __restrict__ bar, int N, int E, int nscan)
{
    const int tid  = threadIdx.x;
    const int bid  = blockIdx.x;
    const int nblk = gridDim.x;
    const int gsz  = nblk * 1024;

    // phase 1: count in-degrees
    for (int e = bid * 1024 + tid; e < E; e += gsz)
        atomicAdd(&cnt[ei[E + e]], 1);

    gbar(&bar[0], nblk);

    // phase 2: block-local inclusive scan (blocks [0, nscan)), dinv
    if (bid < nscan) {
        __shared__ int wsum[16];
        const int lane = tid & 63, wid = tid >> 6;
        const int i = bid * 1024 + tid;
        int v = (i < N) ? cnt[i] : 0;
        int s = v;
        for (int off = 1; off < 64; off <<= 1) {
            int t = __shfl_up(s, off, 64);
            if (lane >= off) s += t;
        }
        if (lane == 63) wsum[wid] = s;
        __syncthreads();
        int woff = 0, total = 0;
#pragma unroll
        for (int w2 = 0; w2 < 16; ++w2) {
            int t = wsum[w2];
            if (w2 < wid) woff += t;
            total += t;
        }
        if (i < N) {
            rp[i + 1] = woff + s;
            dinv[i] = rsqrtf((float)(v + 1));   // +1 self-loop
        }
        if (tid == 0) bsum[bid] = total;
    }

    gbar(&bar[1], nblk);

    // phase 3: add exclusive prefix of block sums
    if (bid < nscan) {
        __shared__ int boff_s;
        if (tid < 64) {
            int v = (tid < bid) ? bsum[tid] : 0;   // nscan <= 64
            for (int off = 32; off > 0; off >>= 1) v += __shfl_down(v, off, 64);
            if (tid == 0) boff_s = v;
        }
        __syncthreads();
        const int i = bid * 1024 + tid;
        if (i < N) rp[i + 1] += boff_s;
        if (i == 0) rp[0] = 0;
    }

    gbar(&bar[2], nblk);

    // phase 4: fill CSR with {src, dinv[src]}; consume cnt as cursor (ends at 0)
    for (int e = bid * 1024 + tid; e < E; e += gsz) {
        int s = ei[e], d = ei[E + e];
        int old = atomicSub(&cnt[d], 1);        // old in [1..deg]
        csr[rp[d] + old - 1] = make_int2(s, __float_as_int(dinv[s]));
    }
}

// ---------------- dense h = x @ W^T  (bf16 MFMA, fp32 accum, bf16 h out) ----
// h stored node-interleaved: h[n][m][128] -> each node's 4 matrix rows are 1 KB contiguous.

__global__ __launch_bounds__(256) void k_gemm(
    const float* __restrict__ x0, const float* __restrict__ x1,
    const float* __restrict__ x2, const float* __restrict__ x3,
    const float* __restrict__ W1, const float* __restrict__ W2,
    unsigned short* __restrict__ h, int N)
{
    const int m = blockIdx.y;
    const float* x = (m == 0) ? x0 : (m == 1) ? x1 : (m == 2) ? x2 : x3;
    const float* W = (m & 1) ? W2 : W1;   // m=0,2 -> W1 ; m=1,3 -> W2

    __shared__ unsigned short Ws[128 * 128];   // [c][k] bf16, 32 KB
    __shared__ unsigned short ts[64 * 136];    // stage stride 128; epilogue stride 136

    const int tid = threadIdx.x;
    const int n0 = blockIdx.x * 64;

    // stage W -> bf16 LDS
    for (int t = tid; t < 128 * 128 / 4; t += 256) {
        float4 v = ((const float4*)W)[t];
        ushort4 b;
        b.x = f2bf(v.x); b.y = f2bf(v.y); b.z = f2bf(v.z); b.w = f2bf(v.w);
        *(ushort4*)&Ws[t * 4] = b;
    }
    // stage x tile -> bf16 LDS (64 rows x 128 cols, stride 128)
    for (int t = tid; t < 64 * 32; t += 256) {
        int r = t >> 5;
        int n = n0 + r;
        float4 v = make_float4(0.f, 0.f, 0.f, 0.f);
        if (n < N) v = ((const float4*)(x + (size_t)n * DD))[t & 31];
        ushort4 b;
        b.x = f2bf(v.x); b.y = f2bf(v.y); b.z = f2bf(v.z); b.w = f2bf(v.w);
        *(ushort4*)&ts[r * 128 + (t & 31) * 4] = b;
    }
    __syncthreads();

    const int w    = tid >> 6;
    const int lane = tid & 63;
    const int am   = lane & 15;
    const int aq   = lane >> 4;
    const int r0   = w * 16;

    f32x4 acc[8] = {};
#pragma unroll
    for (int kk = 0; kk < 128; kk += 32) {
        bf16x8 af = *(const bf16x8*)&ts[(r0 + am) * 128 + kk + aq * 8];
#pragma unroll
        for (int ct = 0; ct < 8; ++ct) {
            bf16x8 bf = *(const bf16x8*)&Ws[(ct * 16 + am) * 128 + kk + aq * 8];
            acc[ct] = __builtin_amdgcn_mfma_f32_16x16x32_bf16(af, bf, acc[ct], 0, 0, 0);
        }
    }
    __syncthreads();   // all waves done reading ts before epilogue overwrite

    // C/D layout: col = lane&15, row = (lane>>4)*4 + reg  -> bf16 into ts (stride 136)
    const int cc = lane & 15;
    const int rr = (lane >> 4) * 4;
#pragma unroll
    for (int ct = 0; ct < 8; ++ct)
#pragma unroll
        for (int i = 0; i < 4; ++i)
            ts[(r0 + rr + i) * 136 + ct * 16 + cc] = f2bf(acc[ct][i]);
    __syncthreads();

    // coalesced store into interleaved layout: h[(n*4 + m)*128 + c]
#pragma unroll
    for (int k = 0; k < 4; ++k) {
        int f = k * 256 + tid;
        int row = f >> 4, ch = f & 15;
        int n = n0 + row;
        if (n < N) {
            uint4 v = *(const uint4*)&ts[row * 136 + ch * 8];
            *(uint4*)(h + ((size_t)n * 4 + m) * DD + ch * 8) = v;
        }
    }
}

// ---------------- aggregation: gather by dst via CSR (interleaved bf16 h) -----
// one block per node; 4 waves each own a contiguous quarter of the edge list;
// lane owns 16 B (8 cols of one matrix) -> one wave VMEM instr reads a full 1 KB row.
// unroll 4 -> 16 rows in flight per block. csr carries {src, dinv[src]} so the
// per-edge chain is csr -> h (no dependent dinv load).

static __device__ __forceinline__ void acc8(float* a, uint4 v, float wt) {
    a[0] += __uint_as_float(v.x << 16) * wt;
    a[1] += __uint_as_float(v.x & 0xffff0000u) * wt;
    a[2] += __uint_as_float(v.y << 16) * wt;
    a[3] += __uint_as_float(v.y & 0xffff0000u) * wt;
    a[4] += __uint_as_float(v.z << 16) * wt;
    a[5] += __uint_as_float(v.z & 0xffff0000u) * wt;
    a[6] += __uint_as_float(v.w << 16) * wt;
    a[7] += __uint_as_float(v.w & 0xffff0000u) * wt;
}

__global__ __launch_bounds__(256) void k_gather(
    const int* __restrict__ rp, const int2* __restrict__ csr,
    const float* __restrict__ dinv, const unsigned short* __restrict__ h,
    const float* __restrict__ b1, const float* __restrict__ b2,
    float* __restrict__ out, int N)
{
    const int n    = blockIdx.x;
    const int tid  = threadIdx.x;
    const int w    = tid >> 6;           // wave 0..3: edge-list quarter
    const int lane = tid & 63;
    const int m    = lane >> 4;          // matrix 0..3
    const int c    = (lane & 15) * 8;    // col base (8 floats)
    const size_t off = (size_t)lane * 8; // ushort offset within 512-wide node row

    const float dn = dinv[n];
    float a[8] = {};

    if (w == 3) {   // self-loop + bias (wave 3's quarter is the short one)
        const float sn = dn * dn;
        const float* bb = (m & 1) ? b2 : b1;
        uint4 hv = *(const uint4*)(h + (size_t)n * 512 + off);
        acc8(a, hv, sn);
        float4 bv0 = *(const float4*)(bb + c);
        float4 bv1 = *(const float4*)(bb + c + 4);
        a[0] += bv0.x; a[1] += bv0.y; a[2] += bv0.z; a[3] += bv0.w;
        a[4] += bv1.x; a[5] += bv1.y; a[6] += bv1.z; a[7] += bv1.w;
    }

    const int j0 = rp[n], j1 = rp[n + 1];
    const int q  = (j1 - j0 + 3) >> 2;
    int jb = j0 + w * q;
    int je = jb + q; if (je > j1) je = j1;

    for (; jb + 3 < je; jb += 4) {
        int2 e0 = csr[jb], e1 = csr[jb + 1], e2 = csr[jb + 2], e3 = csr[jb + 3];
        float w0 = __int_as_float(e0.y) * dn, w1 = __int_as_float(e1.y) * dn,
              w2 = __int_as_float(e2.y) * dn, w3 = __int_as_float(e3.y) * dn;
        uint4 v0 = *(const uint4*)(h + (size_t)e0.x * 512 + off);
        uint4 v1 = *(const uint4*)(h + (size_t)e1.x * 512 + off);
        uint4 v2 = *(const uint4*)(h + (size_t)e2.x * 512 + off);
        uint4 v3 = *(const uint4*)(h + (size_t)e3.x * 512 + off);
        acc8(a, v0, w0); acc8(a, v1, w1); acc8(a, v2, w2); acc8(a, v3, w3);
    }
    for (; jb < je; ++jb) {
        int2 e = csr[jb];
        float wt = __int_as_float(e.y) * dn;
        uint4 v = *(const uint4*)(h + (size_t)e.x * 512 + off);
        acc8(a, v, wt);
    }

    __shared__ float part[3][64][8];     // 6 KB
    if (w) {
        *(f32x4*)&part[w - 1][lane][0] = *(f32x4*)&a[0];
        *(f32x4*)&part[w - 1][lane][4] = *(f32x4*)&a[4];
    }
    __syncthreads();
    if (w == 0) {
#pragma unroll
        for (int k = 0; k < 3; ++k)
#pragma unroll
            for (int i = 0; i < 8; ++i) a[i] += part[k][lane][i];
        float* po = out + ((size_t)m * N + n) * DD + c;
        f32x4 r0, r1;
        r0.x = a[0]; r0.y = a[1]; r0.z = a[2]; r0.w = a[3];
        r1.x = a[4]; r1.y = a[5]; r1.z = a[6]; r1.w = a[7];
        // streaming store: out is never re-read -> keep L2/L3 for h gathers
        __builtin_nontemporal_store(r0, (f32x4*)po);
        __builtin_nontemporal_store(r1, (f32x4*)(po + 4));
    }
}

// ---------------- launch ----------------

extern "C" void kernel_launch(void* const* d_in, const int* in_sizes, int n_in,
                              void* d_out, int out_size, void* d_ws, size_t ws_size,
                              hipStream_t stream) {
    const float* x0 = (const float*)d_in[0];
    const float* x1 = (const float*)d_in[1];
    const float* x2 = (const float*)d_in[2];
    const float* x3 = (const float*)d_in[3];
    const int*   ei = (const int*)d_in[4];
    const float* W1 = (const float*)d_in[5];
    const float* b1 = (const float*)d_in[6];
    const float* W2 = (const float*)d_in[7];
    const float* b2 = (const float*)d_in[8];
    float* out = (float*)d_out;

    const int N = in_sizes[0] / DD;   // 50000
    const int E = in_sizes[4] / 2;    // 800000

    // workspace layout (cnt and bar adjacent -> one memset zeroes both)
    int*   cnt  = (int*)d_ws;                        // 65536
    int*   bar  = cnt + 65536;                       // 64
    int*   rp   = bar + 64;                          // 65536 (needs N+1)
    float* dinv = (float*)(rp + 65536);              // 65536
    int*   bsum = (int*)(dinv + 65536);              // 256
    int2*  csr  = (int2*)(bsum + 256);               // E int2 {src, dinv[src]}
    unsigned short* h = (unsigned short*)(csr + E);  // interleaved [N][4][128] bf16 = 51.2 MB

    const int nscan = (N + 1023) / 1024;             // 49
    const int nblk  = 256;                           // co-resident: 256 x 1024 thr

    hipMemsetAsync(cnt, 0, (65536 + 64) * sizeof(int), stream);
    k_build<<<nblk, 1024, 0, stream>>>(ei, cnt, rp, dinv, bsum, csr, bar, N, E, nscan);

    dim3 g((N + 63) / 64, 4);
    k_gemm<<<g, 256, 0, stream>>>(x0, x1, x2, x3, W1, W2, h, N);

    k_gather<<<N, 256, 0, stream>>>(rp, csr, dinv, h, b1, b2, out, N);
}

// Round 5
// 427.585 us; speedup vs baseline: 1.1087x; 1.1087x over previous
//
#include <hip/hip_runtime.h>

#define DD 128

typedef __bf16 bf16x8 __attribute__((ext_vector_type(8)));
typedef float f32x4 __attribute__((ext_vector_type(4)));

static __device__ __forceinline__ unsigned short f2bf(float f) {
    unsigned int u = __float_as_uint(f);
    u += 0x7FFF + ((u >> 16) & 1);   // round-to-nearest-even
    return (unsigned short)(u >> 16);
}

// ---------------- CSR build (separate kernels: max TLP per phase) ----------

__global__ void k_zero(int* __restrict__ p, int n) {
    int i = blockIdx.x * 256 + threadIdx.x;
    if (i < n) p[i] = 0;
}

__global__ void k_count(const int* __restrict__ dst, int* __restrict__ cnt, int E) {
    int e = blockIdx.x * 256 + threadIdx.x;
    if (e < E) atomicAdd(&cnt[dst[e]], 1);
}

// scan phase 1: block-local inclusive scan into rp[i+1], block totals into bsum,
// dinv = rsqrt(deg+1). Blocks >= nscan piggyback the one-time W f32->bf16 conversion.
__global__ __launch_bounds__(1024) void k_scan1(const int* __restrict__ cnt,
                                                int* __restrict__ rp,
                                                float* __restrict__ dinv,
                                                int* __restrict__ bsum,
                                                const float* __restrict__ W1,
                                                const float* __restrict__ W2,
                                                unsigned short* __restrict__ wbf,
                                                int N, int nscan) {
    const int bid = blockIdx.x;
    if (bid >= nscan) {
        // W conversion: 8 blocks x 1024 threads x 1 float4 = 32768 elems (W1+W2)
        int i = (bid - nscan) * 1024 + threadIdx.x;   // 0..8191
        float4 v = (i < 4096) ? ((const float4*)W1)[i] : ((const float4*)W2)[i - 4096];
        ushort4 b;
        b.x = f2bf(v.x); b.y = f2bf(v.y); b.z = f2bf(v.z); b.w = f2bf(v.w);
        *(ushort4*)&wbf[(size_t)i * 4] = b;
        return;
    }
    __shared__ int wsum[16];
    const int tid = threadIdx.x, lane = tid & 63, wid = tid >> 6;
    const int i = bid * 1024 + tid;
    int v = (i < N) ? cnt[i] : 0;
    int s = v;
    for (int off = 1; off < 64; off <<= 1) {
        int t = __shfl_up(s, off, 64);
        if (lane >= off) s += t;
    }
    if (lane == 63) wsum[wid] = s;
    __syncthreads();
    int woff = 0, total = 0;
#pragma unroll
    for (int w2 = 0; w2 < 16; ++w2) {
        int t = wsum[w2];
        if (w2 < wid) woff += t;
        total += t;
    }
    if (i < N) {
        rp[i + 1] = woff + s;                 // block-local inclusive
        dinv[i] = rsqrtf((float)(v + 1));     // +1 self-loop
    }
    if (tid == 0) bsum[bid] = total;
}

// scan phase 2: add exclusive prefix of block sums.
__global__ __launch_bounds__(1024) void k_scan2(const int* __restrict__ bsum,
                                                int* __restrict__ rp, int N) {
    __shared__ int boff_s;
    const int tid = threadIdx.x;
    if (tid < 64) {
        int v = (tid < (int)blockIdx.x) ? bsum[tid] : 0;   // nb <= 49 < 64
        for (int off = 32; off > 0; off >>= 1) v += __shfl_down(v, off, 64);
        if (tid == 0) boff_s = v;
    }
    __syncthreads();
    const int i = blockIdx.x * 1024 + tid;
    if (i < N) rp[i + 1] += boff_s;
    if (i == 0) rp[0] = 0;
}

// fill: consume cnt as cursor via atomicSub; csr = {src, dinv[src]} (short gather chain)
__global__ void k_fill(const int* __restrict__ ei, const int* __restrict__ rp,
                       int* __restrict__ cnt, const float* __restrict__ dinv,
                       int2* __restrict__ csr, int E) {
    int e = blockIdx.x * 256 + threadIdx.x;
    if (e >= E) return;
    int s = ei[e], d = ei[E + e];
    int old = atomicSub(&cnt[d], 1);          // old in [1..deg]
    csr[rp[d] + old - 1] = make_int2(s, __float_as_int(dinv[s]));
}

// ---------------- dense h = x @ W^T  (bf16 MFMA, fp32 accum, bf16 h out) ----
// W pre-converted to bf16 (wbf) -> staging is pure 16B copies, no per-block conversion.
// tile 128 nodes x 128 cols, 512 threads = 8 waves. LDS 66 KB -> 2 blocks/CU.
// h stored node-interleaved: h[n][m][128] (1 KB per node row).

__global__ __launch_bounds__(512) void k_gemm(
    const float* __restrict__ x0, const float* __restrict__ x1,
    const float* __restrict__ x2, const float* __restrict__ x3,
    const unsigned short* __restrict__ wbf,
    unsigned short* __restrict__ h, int N)
{
    const int m = blockIdx.y;
    const float* x = (m == 0) ? x0 : (m == 1) ? x1 : (m == 2) ? x2 : x3;
    const unsigned short* Wg = wbf + (size_t)(m & 1) * 128 * 128;  // m=0,2->W1; 1,3->W2

    __shared__ unsigned short Ws[128 * 128];   // [c][k] bf16, 32 KB
    __shared__ unsigned short ts[128 * 136];   // stage stride 128; epilogue stride 136

    const int tid = threadIdx.x;
    const int n0 = blockIdx.x * 128;

    // stage W: bf16 vector copy (4 x 16B per thread)
#pragma unroll
    for (int t = tid; t < 2048; t += 512)
        ((uint4*)Ws)[t] = ((const uint4*)Wg)[t];
    // stage x tile -> bf16 (128 rows x 128 cols, stride 128); 8 float4 per thread
    for (int t = tid; t < 128 * 32; t += 512) {
        int r = t >> 5;
        int n = n0 + r;
        float4 v = make_float4(0.f, 0.f, 0.f, 0.f);
        if (n < N) v = ((const float4*)(x + (size_t)n * DD))[t & 31];
        ushort4 b;
        b.x = f2bf(v.x); b.y = f2bf(v.y); b.z = f2bf(v.z); b.w = f2bf(v.w);
        *(ushort4*)&ts[r * 128 + (t & 31) * 4] = b;
    }
    __syncthreads();

    const int w    = tid >> 6;       // 8 waves: rows w*16..w*16+15
    const int lane = tid & 63;
    const int am   = lane & 15;
    const int aq   = lane >> 4;
    const int r0   = w * 16;

    f32x4 acc[8] = {};
#pragma unroll
    for (int kk = 0; kk < 128; kk += 32) {
        bf16x8 af = *(const bf16x8*)&ts[(r0 + am) * 128 + kk + aq * 8];
#pragma unroll
        for (int ct = 0; ct < 8; ++ct) {
            bf16x8 bf = *(const bf16x8*)&Ws[(ct * 16 + am) * 128 + kk + aq * 8];
            acc[ct] = __builtin_amdgcn_mfma_f32_16x16x32_bf16(af, bf, acc[ct], 0, 0, 0);
        }
    }
    __syncthreads();   // all waves done reading ts before epilogue overwrite

    // C/D layout: col = lane&15, row = (lane>>4)*4 + reg  -> bf16 into ts (stride 136)
    const int cc = lane & 15;
    const int rr = (lane >> 4) * 4;
#pragma unroll
    for (int ct = 0; ct < 8; ++ct)
#pragma unroll
        for (int i = 0; i < 4; ++i)
            ts[(r0 + rr + i) * 136 + ct * 16 + cc] = f2bf(acc[ct][i]);
    __syncthreads();

    // coalesced store into interleaved layout: h[(n*4 + m)*128 + c]; 4 x 16B per thread
#pragma unroll
    for (int k = 0; k < 4; ++k) {
        int f = k * 512 + tid;
        int row = f >> 4, ch = f & 15;
        int n = n0 + row;
        if (n < N) {
            uint4 v = *(const uint4*)&ts[row * 136 + ch * 8];
            *(uint4*)(h + ((size_t)n * 4 + m) * DD + ch * 8) = v;
        }
    }
}

// ---------------- aggregation: gather by dst via CSR (interleaved bf16 h) -----
// one block per node; 4 waves each own a contiguous quarter of the edge list;
// lane owns 16 B (8 cols of one matrix) -> one wave VMEM instr reads a full 1 KB row.
// unroll 4 -> 16 rows in flight per block. csr carries {src, dinv[src]} so the
// per-edge chain is csr -> h (no dependent dinv load).

static __device__ __forceinline__ void acc8(float* a, uint4 v, float wt) {
    a[0] += __uint_as_float(v.x << 16) * wt;
    a[1] += __uint_as_float(v.x & 0xffff0000u) * wt;
    a[2] += __uint_as_float(v.y << 16) * wt;
    a[3] += __uint_as_float(v.y & 0xffff0000u) * wt;
    a[4] += __uint_as_float(v.z << 16) * wt;
    a[5] += __uint_as_float(v.z & 0xffff0000u) * wt;
    a[6] += __uint_as_float(v.w << 16) * wt;
    a[7] += __uint_as_float(v.w & 0xffff0000u) * wt;
}

__global__ __launch_bounds__(256) void k_gather(
    const int* __restrict__ rp, const int2* __restrict__ csr,
    const float* __restrict__ dinv, const unsigned short* __restrict__ h,
    const float* __restrict__ b1, const float* __restrict__ b2,
    float* __restrict__ out, int N)
{
    const int n    = blockIdx.x;
    const int tid  = threadIdx.x;
    const int w    = tid >> 6;           // wave 0..3: edge-list quarter
    const int lane = tid & 63;
    const int m    = lane >> 4;          // matrix 0..3
    const int c    = (lane & 15) * 8;    // col base (8 floats)
    const size_t off = (size_t)lane * 8; // ushort offset within 512-wide node row

    const float dn = dinv[n];
    float a[8] = {};

    if (w == 3) {   // self-loop + bias (wave 3's quarter is the short one)
        const float sn = dn * dn;
        const float* bb = (m & 1) ? b2 : b1;
        uint4 hv = *(const uint4*)(h + (size_t)n * 512 + off);
        acc8(a, hv, sn);
        float4 bv0 = *(const float4*)(bb + c);
        float4 bv1 = *(const float4*)(bb + c + 4);
        a[0] += bv0.x; a[1] += bv0.y; a[2] += bv0.z; a[3] += bv0.w;
        a[4] += bv1.x; a[5] += bv1.y; a[6] += bv1.z; a[7] += bv1.w;
    }

    const int j0 = rp[n], j1 = rp[n + 1];
    const int q  = (j1 - j0 + 3) >> 2;
    int jb = j0 + w * q;
    int je = jb + q; if (je > j1) je = j1;

    for (; jb + 3 < je; jb += 4) {
        int2 e0 = csr[jb], e1 = csr[jb + 1], e2 = csr[jb + 2], e3 = csr[jb + 3];
        float w0 = __int_as_float(e0.y) * dn, w1 = __int_as_float(e1.y) * dn,
              w2 = __int_as_float(e2.y) * dn, w3 = __int_as_float(e3.y) * dn;
        uint4 v0 = *(const uint4*)(h + (size_t)e0.x * 512 + off);
        uint4 v1 = *(const uint4*)(h + (size_t)e1.x * 512 + off);
        uint4 v2 = *(const uint4*)(h + (size_t)e2.x * 512 + off);
        uint4 v3 = *(const uint4*)(h + (size_t)e3.x * 512 + off);
        acc8(a, v0, w0); acc8(a, v1, w1); acc8(a, v2, w2); acc8(a, v3, w3);
    }
    for (; jb < je; ++jb) {
        int2 e = csr[jb];
        float wt = __int_as_float(e.y) * dn;
        uint4 v = *(const uint4*)(h + (size_t)e.x * 512 + off);
        acc8(a, v, wt);
    }

    __shared__ float part[3][64][8];     // 6 KB
    if (w) {
        *(f32x4*)&part[w - 1][lane][0] = *(f32x4*)&a[0];
        *(f32x4*)&part[w - 1][lane][4] = *(f32x4*)&a[4];
    }
    __syncthreads();
    if (w == 0) {
#pragma unroll
        for (int k = 0; k < 3; ++k)
#pragma unroll
            for (int i = 0; i < 8; ++i) a[i] += part[k][lane][i];
        float* po = out + ((size_t)m * N + n) * DD + c;
        f32x4 r0, r1;
        r0.x = a[0]; r0.y = a[1]; r0.z = a[2]; r0.w = a[3];
        r1.x = a[4]; r1.y = a[5]; r1.z = a[6]; r1.w = a[7];
        // streaming store: out is never re-read -> keep L2/L3 for h gathers
        __builtin_nontemporal_store(r0, (f32x4*)po);
        __builtin_nontemporal_store(r1, (f32x4*)(po + 4));
    }
}

// ---------------- launch ----------------

extern "C" void kernel_launch(void* const* d_in, const int* in_sizes, int n_in,
                              void* d_out, int out_size, void* d_ws, size_t ws_size,
                              hipStream_t stream) {
    const float* x0 = (const float*)d_in[0];
    const float* x1 = (const float*)d_in[1];
    const float* x2 = (const float*)d_in[2];
    const float* x3 = (const float*)d_in[3];
    const int*   ei = (const int*)d_in[4];
    const float* W1 = (const float*)d_in[5];
    const float* b1 = (const float*)d_in[6];
    const float* W2 = (const float*)d_in[7];
    const float* b2 = (const float*)d_in[8];
    float* out = (float*)d_out;

    const int N = in_sizes[0] / DD;   // 50000
    const int E = in_sizes[4] / 2;    // 800000

    // workspace layout
    int*   cnt  = (int*)d_ws;                        // 65536 ints
    int*   rp   = cnt + 65536;                       // 65536 (needs N+1)
    float* dinv = (float*)(rp + 65536);              // 65536
    int*   bsum = (int*)(dinv + 65536);              // 256
    unsigned short* wbf = (unsigned short*)(bsum + 256);  // 2*128*128 bf16 = 64 KB
    int2*  csr  = (int2*)(wbf + 2 * 128 * 128);      // E int2 {src, dinv[src]}
    unsigned short* h = (unsigned short*)(csr + E);  // interleaved [N][4][128] bf16 = 51.2 MB

    const int nscan = (N + 1023) / 1024;             // 49

    k_zero <<<(N + 255) / 256, 256, 0, stream>>>(cnt, N);
    k_count<<<(E + 255) / 256, 256, 0, stream>>>(ei + E, cnt, E);
    k_scan1<<<nscan + 8, 1024, 0, stream>>>(cnt, rp, dinv, bsum, W1, W2, wbf, N, nscan);
    k_scan2<<<nscan, 1024, 0, stream>>>(bsum, rp, N);
    k_fill <<<(E + 255) / 256, 256, 0, stream>>>(ei, rp, cnt, dinv, csr, E);

    dim3 g((N + 127) / 128, 4);
    k_gemm<<<g, 512, 0, stream>>>(x0, x1, x2, x3, wbf, h, N);

    k_gather<<<N, 256, 0, stream>>>(rp, csr, dinv, h, b1, b2, out, N);
}

// Round 6
// 418.758 us; speedup vs baseline: 1.1320x; 1.0211x over previous
//
#include <hip/hip_runtime.h>

#define DD 128

typedef __bf16 bf16x8 __attribute__((ext_vector_type(8)));
typedef float f32x4 __attribute__((ext_vector_type(4)));

static __device__ __forceinline__ unsigned short f2bf(float f) {
    unsigned int u = __float_as_uint(f);
    u += 0x7FFF + ((u >> 16) & 1);   // round-to-nearest-even
    return (unsigned short)(u >> 16);
}

// ---------------- CSR build ----------------

__global__ void k_count(const int* __restrict__ dst, int* __restrict__ cnt, int E) {
    int e4 = (blockIdx.x * 256 + threadIdx.x) * 4;
    if (e4 < E) {                     // E % 4 == 0
        int4 d = *(const int4*)&dst[e4];
        atomicAdd(&cnt[d.x], 1); atomicAdd(&cnt[d.y], 1);
        atomicAdd(&cnt[d.z], 1); atomicAdd(&cnt[d.w], 1);
    }
}

// scan phase 1: block-local inclusive scan into rp[i+1], block totals into bsum,
// dinv = rsqrt(deg+1). Blocks >= nscan piggyback the one-time W f32->bf16 conversion.
__global__ __launch_bounds__(1024) void k_scan1(const int* __restrict__ cnt,
                                                int* __restrict__ rp,
                                                float* __restrict__ dinv,
                                                int* __restrict__ bsum,
                                                const float* __restrict__ W1,
                                                const float* __restrict__ W2,
                                                unsigned short* __restrict__ wbf,
                                                int N, int nscan) {
    const int bid = blockIdx.x;
    if (bid >= nscan) {
        // W conversion: 8 blocks x 1024 threads x 1 float4 = 32768 elems (W1+W2)
        int i = (bid - nscan) * 1024 + threadIdx.x;   // 0..8191
        float4 v = (i < 4096) ? ((const float4*)W1)[i] : ((const float4*)W2)[i - 4096];
        ushort4 b;
        b.x = f2bf(v.x); b.y = f2bf(v.y); b.z = f2bf(v.z); b.w = f2bf(v.w);
        *(ushort4*)&wbf[(size_t)i * 4] = b;
        return;
    }
    __shared__ int wsum[16];
    const int tid = threadIdx.x, lane = tid & 63, wid = tid >> 6;
    const int i = bid * 1024 + tid;
    int v = (i < N) ? cnt[i] : 0;
    int s = v;
    for (int off = 1; off < 64; off <<= 1) {
        int t = __shfl_up(s, off, 64);
        if (lane >= off) s += t;
    }
    if (lane == 63) wsum[wid] = s;
    __syncthreads();
    int woff = 0, total = 0;
#pragma unroll
    for (int w2 = 0; w2 < 16; ++w2) {
        int t = wsum[w2];
        if (w2 < wid) woff += t;
        total += t;
    }
    if (i < N) {
        rp[i + 1] = woff + s;                 // block-local inclusive
        dinv[i] = rsqrtf((float)(v + 1));     // +1 self-loop
    }
    if (tid == 0) bsum[bid] = total;
}

// scan phase 2: add exclusive prefix of block sums.
__global__ __launch_bounds__(1024) void k_scan2(const int* __restrict__ bsum,
                                                int* __restrict__ rp, int N) {
    __shared__ int boff_s;
    const int tid = threadIdx.x;
    if (tid < 64) {
        int v = (tid < (int)blockIdx.x) ? bsum[tid] : 0;   // nb <= 49 < 64
        for (int off = 32; off > 0; off >>= 1) v += __shfl_down(v, off, 64);
        if (tid == 0) boff_s = v;
    }
    __syncthreads();
    const int i = blockIdx.x * 1024 + tid;
    if (i < N) rp[i + 1] += boff_s;
    if (i == 0) rp[0] = 0;
}

// fill: consume cnt as cursor via atomicSub; csr = {src, dinv[src]}; 2 edges/thread
__global__ void k_fill(const int* __restrict__ ei, const int* __restrict__ rp,
                       int* __restrict__ cnt, const float* __restrict__ dinv,
                       int2* __restrict__ csr, int E) {
    int e2 = (blockIdx.x * 256 + threadIdx.x) * 2;
    if (e2 >= E) return;              // E % 2 == 0
    int2 s = *(const int2*)&ei[e2];
    int2 d = *(const int2*)&ei[E + e2];
    int o0 = atomicSub(&cnt[d.x], 1);         // old in [1..deg]
    csr[rp[d.x] + o0 - 1] = make_int2(s.x, __float_as_int(dinv[s.x]));
    int o1 = atomicSub(&cnt[d.y], 1);
    csr[rp[d.y] + o1 - 1] = make_int2(s.y, __float_as_int(dinv[s.y]));
}

// ---------------- dense h = x @ W^T  (bf16 MFMA, fp32 accum, bf16 h out) ----
// W pre-converted to bf16 (wbf). LDS tiles XOR-swizzled (T2): ushort_off ^= (row&7)<<3
// kills the 256B-row-stride bank aliasing on ds_read_b128 fragment reads.
// tile 128 nodes x 128 cols, 512 threads = 8 waves; h[n][m][128] interleaved.

__global__ __launch_bounds__(512) void k_gemm(
    const float* __restrict__ x0, const float* __restrict__ x1,
    const float* __restrict__ x2, const float* __restrict__ x3,
    const unsigned short* __restrict__ wbf,
    unsigned short* __restrict__ h, int N)
{
    const int m = blockIdx.y;
    const float* x = (m == 0) ? x0 : (m == 1) ? x1 : (m == 2) ? x2 : x3;
    const unsigned short* Wg = wbf + (size_t)(m & 1) * 128 * 128;  // m=0,2->W1; 1,3->W2

    __shared__ unsigned short Ws[128 * 128];   // [c][k] bf16, swizzled, 32 KB
    __shared__ unsigned short ts[128 * 136];   // stage stride 128 swizzled; epilogue 136

    const int tid = threadIdx.x;
    const int n0 = blockIdx.x * 128;

    // stage W: 16B copies with swizzle (uint4 index t -> t ^ ((t>>4)&7))
#pragma unroll
    for (int t = tid; t < 2048; t += 512)
        ((uint4*)Ws)[t ^ ((t >> 4) & 7)] = ((const uint4*)Wg)[t];
    // stage x tile -> bf16 (128 rows x 128 cols, stride 128, swizzled)
    for (int t = tid; t < 128 * 32; t += 512) {
        int r = t >> 5;
        int n = n0 + r;
        float4 v = make_float4(0.f, 0.f, 0.f, 0.f);
        if (n < N) v = ((const float4*)(x + (size_t)n * DD))[t & 31];
        ushort4 b;
        b.x = f2bf(v.x); b.y = f2bf(v.y); b.z = f2bf(v.z); b.w = f2bf(v.w);
        *(ushort4*)&ts[r * 128 + (((t & 31) * 4) ^ ((r & 7) << 3))] = b;
    }
    __syncthreads();

    const int w    = tid >> 6;       // 8 waves: rows w*16..w*16+15
    const int lane = tid & 63;
    const int am   = lane & 15;
    const int aq   = lane >> 4;
    const int r0   = w * 16;

    f32x4 acc[8] = {};
#pragma unroll
    for (int kk = 0; kk < 128; kk += 32) {
        const int ar = r0 + am;
        bf16x8 af = *(const bf16x8*)&ts[ar * 128 + ((kk + aq * 8) ^ ((ar & 7) << 3))];
#pragma unroll
        for (int ct = 0; ct < 8; ++ct) {
            bf16x8 bf = *(const bf16x8*)&Ws[(ct * 16 + am) * 128 +
                                            ((kk + aq * 8) ^ ((am & 7) << 3))];
            acc[ct] = __builtin_amdgcn_mfma_f32_16x16x32_bf16(af, bf, acc[ct], 0, 0, 0);
        }
    }
    __syncthreads();   // all waves done reading ts before epilogue overwrite

    // C/D layout: col = lane&15, row = (lane>>4)*4 + reg  -> bf16 into ts (stride 136)
    const int cc = lane & 15;
    const int rr = (lane >> 4) * 4;
#pragma unroll
    for (int ct = 0; ct < 8; ++ct)
#pragma unroll
        for (int i = 0; i < 4; ++i)
            ts[(r0 + rr + i) * 136 + ct * 16 + cc] = f2bf(acc[ct][i]);
    __syncthreads();

    // coalesced store into interleaved layout: h[(n*4 + m)*128 + c]; 4 x 16B per thread
#pragma unroll
    for (int k = 0; k < 4; ++k) {
        int f = k * 512 + tid;
        int row = f >> 4, ch = f & 15;
        int n = n0 + row;
        if (n < N) {
            uint4 v = *(const uint4*)&ts[row * 136 + ch * 8];
            *(uint4*)(h + ((size_t)n * 4 + m) * DD + ch * 8) = v;
        }
    }
}

// ---------------- aggregation: gather by dst via CSR (interleaved bf16 h) -----
// ONE WAVE PER NODE (4 nodes/block): no barriers, no LDS, no partial reduction.
// lane owns 16 B (8 cols of one matrix); one wave VMEM instr = full 1 KB h row.
// unroll 4 -> 4 rows in flight/wave; TLP (32 waves/CU) supplies the rest.

static __device__ __forceinline__ void acc8(float* a, uint4 v, float wt) {
    a[0] += __uint_as_float(v.x << 16) * wt;
    a[1] += __uint_as_float(v.x & 0xffff0000u) * wt;
    a[2] += __uint_as_float(v.y << 16) * wt;
    a[3] += __uint_as_float(v.y & 0xffff0000u) * wt;
    a[4] += __uint_as_float(v.z << 16) * wt;
    a[5] += __uint_as_float(v.z & 0xffff0000u) * wt;
    a[6] += __uint_as_float(v.w << 16) * wt;
    a[7] += __uint_as_float(v.w & 0xffff0000u) * wt;
}

__global__ __launch_bounds__(256) void k_gather(
    const int* __restrict__ rp, const int2* __restrict__ csr,
    const float* __restrict__ dinv, const unsigned short* __restrict__ h,
    const float* __restrict__ b1, const float* __restrict__ b2,
    float* __restrict__ out, int N)
{
    const int n = blockIdx.x * 4 + (threadIdx.x >> 6);
    if (n >= N) return;
    const int lane = threadIdx.x & 63;
    const int m    = lane >> 4;          // matrix 0..3
    const int c    = (lane & 15) * 8;    // col base (8 floats)
    const size_t off = (size_t)lane * 8; // ushort offset within 512-wide node row

    const float dn = dinv[n];
    float a[8];

    // self-loop + bias
    {
        const float sn = dn * dn;
        const float* bb = (m & 1) ? b2 : b1;
        uint4 hv = *(const uint4*)(h + (size_t)n * 512 + off);
        float4 bv0 = *(const float4*)(bb + c);
        float4 bv1 = *(const float4*)(bb + c + 4);
        a[0] = bv0.x; a[1] = bv0.y; a[2] = bv0.z; a[3] = bv0.w;
        a[4] = bv1.x; a[5] = bv1.y; a[6] = bv1.z; a[7] = bv1.w;
        acc8(a, hv, sn);
    }

    int jb = rp[n];
    const int j1 = rp[n + 1];

    for (; jb + 3 < j1; jb += 4) {
        int2 e0 = csr[jb], e1 = csr[jb + 1], e2 = csr[jb + 2], e3 = csr[jb + 3];
        float w0 = __int_as_float(e0.y) * dn, w1 = __int_as_float(e1.y) * dn,
              w2 = __int_as_float(e2.y) * dn, w3 = __int_as_float(e3.y) * dn;
        uint4 v0 = *(const uint4*)(h + (size_t)e0.x * 512 + off);
        uint4 v1 = *(const uint4*)(h + (size_t)e1.x * 512 + off);
        uint4 v2 = *(const uint4*)(h + (size_t)e2.x * 512 + off);
        uint4 v3 = *(const uint4*)(h + (size_t)e3.x * 512 + off);
        acc8(a, v0, w0); acc8(a, v1, w1); acc8(a, v2, w2); acc8(a, v3, w3);
    }
    for (; jb < j1; ++jb) {
        int2 e = csr[jb];
        float wt = __int_as_float(e.y) * dn;
        uint4 v = *(const uint4*)(h + (size_t)e.x * 512 + off);
        acc8(a, v, wt);
    }

    float* po = out + ((size_t)m * N + n) * DD + c;
    f32x4 r0, r1;
    r0.x = a[0]; r0.y = a[1]; r0.z = a[2]; r0.w = a[3];
    r1.x = a[4]; r1.y = a[5]; r1.z = a[6]; r1.w = a[7];
    // streaming store: out is never re-read -> keep L2/L3 for h gathers
    __builtin_nontemporal_store(r0, (f32x4*)po);
    __builtin_nontemporal_store(r1, (f32x4*)(po + 4));
}

// ---------------- launch ----------------

extern "C" void kernel_launch(void* const* d_in, const int* in_sizes, int n_in,
                              void* d_out, int out_size, void* d_ws, size_t ws_size,
                              hipStream_t stream) {
    const float* x0 = (const float*)d_in[0];
    const float* x1 = (const float*)d_in[1];
    const float* x2 = (const float*)d_in[2];
    const float* x3 = (const float*)d_in[3];
    const int*   ei = (const int*)d_in[4];
    const float* W1 = (const float*)d_in[5];
    const float* b1 = (const float*)d_in[6];
    const float* W2 = (const float*)d_in[7];
    const float* b2 = (const float*)d_in[8];
    float* out = (float*)d_out;

    const int N = in_sizes[0] / DD;   // 50000
    const int E = in_sizes[4] / 2;    // 800000

    // workspace layout
    int*   cnt  = (int*)d_ws;                        // 65536 ints
    int*   rp   = cnt + 65536;                       // 65536 (needs N+1)
    float* dinv = (float*)(rp + 65536);              // 65536
    int*   bsum = (int*)(dinv + 65536);              // 256
    unsigned short* wbf = (unsigned short*)(bsum + 256);  // 2*128*128 bf16 = 64 KB
    int2*  csr  = (int2*)(wbf + 2 * 128 * 128);      // E int2 {src, dinv[src]}
    unsigned short* h = (unsigned short*)(csr + E);  // interleaved [N][4][128] bf16 = 51.2 MB

    const int nscan = (N + 1023) / 1024;             // 49

    hipMemsetAsync(cnt, 0, (size_t)N * sizeof(int), stream);
    k_count<<<(E / 4 + 255) / 256, 256, 0, stream>>>(ei + E, cnt, E);
    k_scan1<<<nscan + 8, 1024, 0, stream>>>(cnt, rp, dinv, bsum, W1, W2, wbf, N, nscan);
    k_scan2<<<nscan, 1024, 0, stream>>>(bsum, rp, N);
    k_fill <<<(E / 2 + 255) / 256, 256, 0, stream>>>(ei, rp, cnt, dinv, csr, E);

    dim3 g((N + 127) / 128, 4);
    k_gemm<<<g, 512, 0, stream>>>(x0, x1, x2, x3, wbf, h, N);

    k_gather<<<(N + 3) / 4, 256, 0, stream>>>(rp, csr, dinv, h, b1, b2, out, N);
}

// Round 7
// 405.061 us; speedup vs baseline: 1.1703x; 1.0338x over previous
//
#include <hip/hip_runtime.h>

#define DD 128

typedef __bf16 bf16x8 __attribute__((ext_vector_type(8)));
typedef float f32x4 __attribute__((ext_vector_type(4)));

static __device__ __forceinline__ unsigned short f2bf(float f) {
    unsigned int u = __float_as_uint(f);
    u += 0x7FFF + ((u >> 16) & 1);   // round-to-nearest-even
    return (unsigned short)(u >> 16);
}

// ---------------- CSR build ----------------

__global__ void k_count(const int* __restrict__ dst, int* __restrict__ cnt, int E) {
    int e4 = (blockIdx.x * 256 + threadIdx.x) * 4;
    if (e4 < E) {                     // E % 4 == 0
        int4 d = *(const int4*)&dst[e4];
        atomicAdd(&cnt[d.x], 1); atomicAdd(&cnt[d.y], 1);
        atomicAdd(&cnt[d.z], 1); atomicAdd(&cnt[d.w], 1);
    }
}

// scan phase 1: block-local inclusive scan into rp[i+1], block totals into bsum,
// dinv = rsqrt(deg+1). Blocks >= nscan piggyback the one-time W f32->bf16 conversion.
__global__ __launch_bounds__(1024) void k_scan1(const int* __restrict__ cnt,
                                                int* __restrict__ rp,
                                                float* __restrict__ dinv,
                                                int* __restrict__ bsum,
                                                const float* __restrict__ W1,
                                                const float* __restrict__ W2,
                                                unsigned short* __restrict__ wbf,
                                                int N, int nscan) {
    const int bid = blockIdx.x;
    if (bid >= nscan) {
        // W conversion: 8 blocks x 1024 threads x 1 float4 = 32768 elems (W1+W2)
        int i = (bid - nscan) * 1024 + threadIdx.x;   // 0..8191
        float4 v = (i < 4096) ? ((const float4*)W1)[i] : ((const float4*)W2)[i - 4096];
        ushort4 b;
        b.x = f2bf(v.x); b.y = f2bf(v.y); b.z = f2bf(v.z); b.w = f2bf(v.w);
        *(ushort4*)&wbf[(size_t)i * 4] = b;
        return;
    }
    __shared__ int wsum[16];
    const int tid = threadIdx.x, lane = tid & 63, wid = tid >> 6;
    const int i = bid * 1024 + tid;
    int v = (i < N) ? cnt[i] : 0;
    int s = v;
    for (int off = 1; off < 64; off <<= 1) {
        int t = __shfl_up(s, off, 64);
        if (lane >= off) s += t;
    }
    if (lane == 63) wsum[wid] = s;
    __syncthreads();
    int woff = 0, total = 0;
#pragma unroll
    for (int w2 = 0; w2 < 16; ++w2) {
        int t = wsum[w2];
        if (w2 < wid) woff += t;
        total += t;
    }
    if (i < N) {
        rp[i + 1] = woff + s;                 // block-local inclusive
        dinv[i] = rsqrtf((float)(v + 1));     // +1 self-loop
    }
    if (tid == 0) bsum[bid] = total;
}

// scan phase 2: add exclusive prefix of block sums.
__global__ __launch_bounds__(1024) void k_scan2(const int* __restrict__ bsum,
                                                int* __restrict__ rp, int N) {
    __shared__ int boff_s;
    const int tid = threadIdx.x;
    if (tid < 64) {
        int v = (tid < (int)blockIdx.x) ? bsum[tid] : 0;   // nb <= 49 < 64
        for (int off = 32; off > 0; off >>= 1) v += __shfl_down(v, off, 64);
        if (tid == 0) boff_s = v;
    }
    __syncthreads();
    const int i = blockIdx.x * 1024 + tid;
    if (i < N) rp[i + 1] += boff_s;
    if (i == 0) rp[0] = 0;
}

// fill: consume cnt as cursor via atomicSub; csr = {src, dinv[src]}; 2 edges/thread
__global__ void k_fill(const int* __restrict__ ei, const int* __restrict__ rp,
                       int* __restrict__ cnt, const float* __restrict__ dinv,
                       int2* __restrict__ csr, int E) {
    int e2 = (blockIdx.x * 256 + threadIdx.x) * 2;
    if (e2 >= E) return;              // E % 2 == 0
    int2 s = *(const int2*)&ei[e2];
    int2 d = *(const int2*)&ei[E + e2];
    int o0 = atomicSub(&cnt[d.x], 1);         // old in [1..deg]
    csr[rp[d.x] + o0 - 1] = make_int2(s.x, __float_as_int(dinv[s.x]));
    int o1 = atomicSub(&cnt[d.y], 1);
    csr[rp[d.y] + o1 - 1] = make_int2(s.y, __float_as_int(dinv[s.y]));
}

// ---------------- dense h = x @ W^T  (bf16 MFMA, fp32 accum, bf16 h out) ----
// A path: global -> registers directly (no LDS staging, no barrier for A).
// x loads issued BEFORE W staging so HBM latency hides under it.
// LDS: swizzled Ws (32 KB) + half-tile epilogue buffer (17 KB) -> 3 blocks/CU.
// tile 128 nodes x 128 cols, 512 threads = 8 waves; h[n][m][128] interleaved.

__global__ __launch_bounds__(512) void k_gemm(
    const float* __restrict__ x0, const float* __restrict__ x1,
    const float* __restrict__ x2, const float* __restrict__ x3,
    const unsigned short* __restrict__ wbf,
    unsigned short* __restrict__ h, int N)
{
    const int m = blockIdx.y;
    const float* x = (m == 0) ? x0 : (m == 1) ? x1 : (m == 2) ? x2 : x3;
    const unsigned short* Wg = wbf + (size_t)(m & 1) * 128 * 128;  // m=0,2->W1; 1,3->W2

    __shared__ unsigned short Ws[128 * 128];   // [c][k] bf16, swizzled, 32 KB
    __shared__ unsigned short eb[64 * 136];    // epilogue half-tile, 17 KB

    const int tid  = threadIdx.x;
    const int n0   = blockIdx.x * 128;
    const int w    = tid >> 6;       // 8 waves: rows w*16..w*16+15
    const int lane = tid & 63;
    const int am   = lane & 15;
    const int aq   = lane >> 4;
    const int r0   = w * 16;

    // A: direct global -> regs. Row clamped for OOB: garbage lands only in
    // C rows >= N, which are never stored.
    int arow = n0 + r0 + am; if (arow > N - 1) arow = N - 1;
    const float* xr = x + (size_t)arow * DD + aq * 8;
    float4 a0[4], a1[4];
#pragma unroll
    for (int q = 0; q < 4; ++q) {
        a0[q] = *(const float4*)(xr + q * 32);
        a1[q] = *(const float4*)(xr + q * 32 + 4);
    }

    // stage W: 16B copies with swizzle (uint4 index t -> t ^ ((t>>4)&7))
#pragma unroll
    for (int t = tid; t < 2048; t += 512)
        ((uint4*)Ws)[t ^ ((t >> 4) & 7)] = ((const uint4*)Wg)[t];
    __syncthreads();

    // convert A to bf16 fragments (vmcnt wait lands here, after W staging)
    bf16x8 afr[4];
#pragma unroll
    for (int q = 0; q < 4; ++q) {
        afr[q][0] = (__bf16)a0[q].x; afr[q][1] = (__bf16)a0[q].y;
        afr[q][2] = (__bf16)a0[q].z; afr[q][3] = (__bf16)a0[q].w;
        afr[q][4] = (__bf16)a1[q].x; afr[q][5] = (__bf16)a1[q].y;
        afr[q][6] = (__bf16)a1[q].z; afr[q][7] = (__bf16)a1[q].w;
    }

    f32x4 acc[8] = {};
#pragma unroll
    for (int q = 0; q < 4; ++q) {
        const int kc = q * 32 + aq * 8;
#pragma unroll
        for (int ct = 0; ct < 8; ++ct) {
            bf16x8 bf = *(const bf16x8*)&Ws[(ct * 16 + am) * 128 +
                                            (kc ^ ((am & 7) << 3))];
            acc[ct] = __builtin_amdgcn_mfma_f32_16x16x32_bf16(afr[q], bf, acc[ct], 0, 0, 0);
        }
    }

    // epilogue, two half-tiles through eb (C/D: col = lane&15, row = (lane>>4)*4 + i)
    const int cc = lane & 15;
    const int rr = (lane >> 4) * 4;

    if (w < 4) {                 // rows 0..63
#pragma unroll
        for (int ct = 0; ct < 8; ++ct)
#pragma unroll
            for (int i = 0; i < 4; ++i)
                eb[(r0 + rr + i) * 136 + ct * 16 + cc] = f2bf(acc[ct][i]);
    }
    __syncthreads();
#pragma unroll
    for (int k = 0; k < 2; ++k) {
        int f = k * 512 + tid;             // 64 rows x 16 chunks
        int row2 = f >> 4, ch = f & 15;
        int n = n0 + row2;
        if (n < N)
            *(uint4*)(h + ((size_t)n * 4 + m) * DD + ch * 8) =
                *(const uint4*)&eb[row2 * 136 + ch * 8];
    }
    __syncthreads();
    if (w >= 4) {                // rows 64..127
#pragma unroll
        for (int ct = 0; ct < 8; ++ct)
#pragma unroll
            for (int i = 0; i < 4; ++i)
                eb[(r0 - 64 + rr + i) * 136 + ct * 16 + cc] = f2bf(acc[ct][i]);
    }
    __syncthreads();
#pragma unroll
    for (int k = 0; k < 2; ++k) {
        int f = k * 512 + tid;
        int row2 = f >> 4, ch = f & 15;
        int n = n0 + 64 + row2;
        if (n < N)
            *(uint4*)(h + ((size_t)n * 4 + m) * DD + ch * 8) =
                *(const uint4*)&eb[row2 * 136 + ch * 8];
    }
}

// ---------------- aggregation: gather by dst via CSR (interleaved bf16 h) -----
// ONE WAVE PER NODE (4 nodes/block): no barriers, no LDS.
// lane owns 16 B (8 cols of one matrix); one wave VMEM instr = full 1 KB h row.
// unroll 8 (deg~16 -> 2 batches) + ONE masked tail batch (clamped idx, zero wt).

static __device__ __forceinline__ void acc8(float* a, uint4 v, float wt) {
    a[0] += __uint_as_float(v.x << 16) * wt;
    a[1] += __uint_as_float(v.x & 0xffff0000u) * wt;
    a[2] += __uint_as_float(v.y << 16) * wt;
    a[3] += __uint_as_float(v.y & 0xffff0000u) * wt;
    a[4] += __uint_as_float(v.z << 16) * wt;
    a[5] += __uint_as_float(v.z & 0xffff0000u) * wt;
    a[6] += __uint_as_float(v.w << 16) * wt;
    a[7] += __uint_as_float(v.w & 0xffff0000u) * wt;
}

__global__ __launch_bounds__(256) void k_gather(
    const int* __restrict__ rp, const int2* __restrict__ csr,
    const float* __restrict__ dinv, const unsigned short* __restrict__ h,
    const float* __restrict__ b1, const float* __restrict__ b2,
    float* __restrict__ out, int N)
{
    const int n = blockIdx.x * 4 + (threadIdx.x >> 6);
    if (n >= N) return;
    const int lane = threadIdx.x & 63;
    const int m    = lane >> 4;          // matrix 0..3
    const int c    = (lane & 15) * 8;    // col base (8 floats)
    const size_t off = (size_t)lane * 8; // ushort offset within 512-wide node row

    const float dn = dinv[n];
    float a[8];

    // self-loop + bias
    {
        const float sn = dn * dn;
        const float* bb = (m & 1) ? b2 : b1;
        uint4 hv = *(const uint4*)(h + (size_t)n * 512 + off);
        float4 bv0 = *(const float4*)(bb + c);
        float4 bv1 = *(const float4*)(bb + c + 4);
        a[0] = bv0.x; a[1] = bv0.y; a[2] = bv0.z; a[3] = bv0.w;
        a[4] = bv1.x; a[5] = bv1.y; a[6] = bv1.z; a[7] = bv1.w;
        acc8(a, hv, sn);
    }

    int jb = rp[n];
    const int j1 = rp[n + 1];

    for (; jb + 7 < j1; jb += 8) {
        int2 e0 = csr[jb],     e1 = csr[jb + 1], e2 = csr[jb + 2], e3 = csr[jb + 3];
        int2 e4 = csr[jb + 4], e5 = csr[jb + 5], e6 = csr[jb + 6], e7 = csr[jb + 7];
        float w0 = __int_as_float(e0.y) * dn, w1 = __int_as_float(e1.y) * dn,
              w2 = __int_as_float(e2.y) * dn, w3 = __int_as_float(e3.y) * dn,
              w4 = __int_as_float(e4.y) * dn, w5 = __int_as_float(e5.y) * dn,
              w6 = __int_as_float(e6.y) * dn, w7 = __int_as_float(e7.y) * dn;
        uint4 v0 = *(const uint4*)(h + (size_t)e0.x * 512 + off);
        uint4 v1 = *(const uint4*)(h + (size_t)e1.x * 512 + off);
        uint4 v2 = *(const uint4*)(h + (size_t)e2.x * 512 + off);
        uint4 v3 = *(const uint4*)(h + (size_t)e3.x * 512 + off);
        uint4 v4 = *(const uint4*)(h + (size_t)e4.x * 512 + off);
        uint4 v5 = *(const uint4*)(h + (size_t)e5.x * 512 + off);
        uint4 v6 = *(const uint4*)(h + (size_t)e6.x * 512 + off);
        uint4 v7 = *(const uint4*)(h + (size_t)e7.x * 512 + off);
        acc8(a, v0, w0); acc8(a, v1, w1); acc8(a, v2, w2); acc8(a, v3, w3);
        acc8(a, v4, w4); acc8(a, v5, w5); acc8(a, v6, w6); acc8(a, v7, w7);
    }
    if (jb < j1) {               // one masked batch covers the remainder
        const int last = j1 - 1;
#pragma unroll
        for (int k = 0; k < 8; ++k) {
            int idx = jb + k;
            int2 e = csr[idx <= last ? idx : last];   // clamped: line is hot
            float wt = (idx <= last) ? __int_as_float(e.y) * dn : 0.f;
            uint4 v = *(const uint4*)(h + (size_t)e.x * 512 + off);
            acc8(a, v, wt);
        }
    }

    float* po = out + ((size_t)m * N + n) * DD + c;
    f32x4 r0, r1;
    r0.x = a[0]; r0.y = a[1]; r0.z = a[2]; r0.w = a[3];
    r1.x = a[4]; r1.y = a[5]; r1.z = a[6]; r1.w = a[7];
    // streaming store: out is never re-read -> keep L2/L3 for h gathers
    __builtin_nontemporal_store(r0, (f32x4*)po);
    __builtin_nontemporal_store(r1, (f32x4*)(po + 4));
}

// ---------------- launch ----------------

extern "C" void kernel_launch(void* const* d_in, const int* in_sizes, int n_in,
                              void* d_out, int out_size, void* d_ws, size_t ws_size,
                              hipStream_t stream) {
    const float* x0 = (const float*)d_in[0];
    const float* x1 = (const float*)d_in[1];
    const float* x2 = (const float*)d_in[2];
    const float* x3 = (const float*)d_in[3];
    const int*   ei = (const int*)d_in[4];
    const float* W1 = (const float*)d_in[5];
    const float* b1 = (const float*)d_in[6];
    const float* W2 = (const float*)d_in[7];
    const float* b2 = (const float*)d_in[8];
    float* out = (float*)d_out;

    const int N = in_sizes[0] / DD;   // 50000
    const int E = in_sizes[4] / 2;    // 800000

    // workspace layout
    int*   cnt  = (int*)d_ws;                        // 65536 ints
    int*   rp   = cnt + 65536;                       // 65536 (needs N+1)
    float* dinv = (float*)(rp + 65536);              // 65536
    int*   bsum = (int*)(dinv + 65536);              // 256
    unsigned short* wbf = (unsigned short*)(bsum + 256);  // 2*128*128 bf16 = 64 KB
    int2*  csr  = (int2*)(wbf + 2 * 128 * 128);      // E int2 {src, dinv[src]}
    unsigned short* h = (unsigned short*)(csr + E);  // interleaved [N][4][128] bf16 = 51.2 MB

    const int nscan = (N + 1023) / 1024;             // 49

    hipMemsetAsync(cnt, 0, (size_t)N * sizeof(int), stream);
    k_count<<<(E / 4 + 255) / 256, 256, 0, stream>>>(ei + E, cnt, E);
    k_scan1<<<nscan + 8, 1024, 0, stream>>>(cnt, rp, dinv, bsum, W1, W2, wbf, N, nscan);
    k_scan2<<<nscan, 1024, 0, stream>>>(bsum, rp, N);
    k_fill <<<(E / 2 + 255) / 256, 256, 0, stream>>>(ei, rp, cnt, dinv, csr, E);

    dim3 g((N + 127) / 128, 4);
    k_gemm<<<g, 512, 0, stream>>>(x0, x1, x2, x3, wbf, h, N);

    k_gather<<<(N + 3) / 4, 256, 0, stream>>>(rp, csr, dinv, h, b1, b2, out, N);
}

// Round 8
// 394.919 us; speedup vs baseline: 1.2004x; 1.0257x over previous
//
#include <hip/hip_runtime.h>

#define DD 128

typedef __bf16 bf16x8 __attribute__((ext_vector_type(8)));
typedef float f32x4 __attribute__((ext_vector_type(4)));

static __device__ __forceinline__ unsigned short f2bf(float f) {
    unsigned int u = __float_as_uint(f);
    u += 0x7FFF + ((u >> 16) & 1);   // round-to-nearest-even
    return (unsigned short)(u >> 16);
}

// ---------------- front: W f32->bf16 conversion (blocks 0..7) || degree count ----

__global__ __launch_bounds__(1024) void k_front(
    const int* __restrict__ dst, int* __restrict__ cnt,
    const float* __restrict__ W1, const float* __restrict__ W2,
    unsigned short* __restrict__ wbf, int E)
{
    const int bid = blockIdx.x;
    if (bid < 8) {
        // W conversion: 8 blocks x 1024 threads x 1 float4 = 32768 elems (W1+W2)
        int i = bid * 1024 + threadIdx.x;   // 0..8191
        float4 v = (i < 4096) ? ((const float4*)W1)[i] : ((const float4*)W2)[i - 4096];
        ushort4 b;
        b.x = f2bf(v.x); b.y = f2bf(v.y); b.z = f2bf(v.z); b.w = f2bf(v.w);
        *(ushort4*)&wbf[(size_t)i * 4] = b;
        return;
    }
    int e4 = ((bid - 8) * 1024 + threadIdx.x) * 4;
    if (e4 < E) {                     // E % 4 == 0
        int4 d = *(const int4*)&dst[e4];
        atomicAdd(&cnt[d.x], 1); atomicAdd(&cnt[d.y], 1);
        atomicAdd(&cnt[d.z], 1); atomicAdd(&cnt[d.w], 1);
    }
}

// ---------------- scan phase 1: block-local inclusive scan, dinv ----------

__global__ __launch_bounds__(1024) void k_scan1(const int* __restrict__ cnt,
                                                int* __restrict__ rp,
                                                float* __restrict__ dinv,
                                                int* __restrict__ bsum, int N) {
    __shared__ int wsum[16];
    const int tid = threadIdx.x, lane = tid & 63, wid = tid >> 6;
    const int i = blockIdx.x * 1024 + tid;
    int v = (i < N) ? cnt[i] : 0;
    int s = v;
    for (int off = 1; off < 64; off <<= 1) {
        int t = __shfl_up(s, off, 64);
        if (lane >= off) s += t;
    }
    if (lane == 63) wsum[wid] = s;
    __syncthreads();
    int woff = 0, total = 0;
#pragma unroll
    for (int w2 = 0; w2 < 16; ++w2) {
        int t = wsum[w2];
        if (w2 < wid) woff += t;
        total += t;
    }
    if (i < N) {
        rp[i + 1] = woff + s;                 // block-local inclusive
        dinv[i] = rsqrtf((float)(v + 1));     // +1 self-loop
    }
    if (tid == 0) bsum[blockIdx.x] = total;
}

// scan phase 2: add exclusive prefix of block sums.
__global__ __launch_bounds__(1024) void k_scan2(const int* __restrict__ bsum,
                                                int* __restrict__ rp, int N) {
    __shared__ int boff_s;
    const int tid = threadIdx.x;
    if (tid < 64) {
        int v = (tid < (int)blockIdx.x) ? bsum[tid] : 0;   // nb <= 49 < 64
        for (int off = 32; off > 0; off >>= 1) v += __shfl_down(v, off, 64);
        if (tid == 0) boff_s = v;
    }
    __syncthreads();
    const int i = blockIdx.x * 1024 + tid;
    if (i < N) rp[i + 1] += boff_s;
    if (i == 0) rp[0] = 0;
}

// ---------------- mid: dense gemm (blocks [0, GB)) || CSR fill (blocks [GB, ...)) ----
// Fill is pure latency/atomic work; gemm is pure BW/MFMA work -> fill hides
// under gemm. The two are dataflow-independent (fill: rp/cnt/dinv; gemm: wbf/x).
//
// gemm: A path global -> registers directly; LDS = single 128x136 union buffer
// (Ws swizzled view during MFMA, epilogue view after). h[n][m][128] interleaved.

__global__ __launch_bounds__(512) void k_mid(
    const float* __restrict__ x0, const float* __restrict__ x1,
    const float* __restrict__ x2, const float* __restrict__ x3,
    const unsigned short* __restrict__ wbf,
    unsigned short* __restrict__ h,
    const int* __restrict__ ei, const int* __restrict__ rp,
    int* __restrict__ cnt, const float* __restrict__ dinv,
    int2* __restrict__ csr,
    int N, int E, int GB)
{
    const int bid = blockIdx.x;
    const int tid = threadIdx.x;

    if (bid >= GB) {
        // ---- fill: consume cnt as cursor via atomicSub; 2 edges/thread ----
        int e2 = ((bid - GB) * 512 + tid) * 2;
        if (e2 >= E) return;          // E % 2 == 0
        int2 s = *(const int2*)&ei[e2];
        int2 d = *(const int2*)&ei[E + e2];
        int o0 = atomicSub(&cnt[d.x], 1);         // old in [1..deg]
        csr[rp[d.x] + o0 - 1] = make_int2(s.x, __float_as_int(dinv[s.x]));
        int o1 = atomicSub(&cnt[d.y], 1);
        csr[rp[d.y] + o1 - 1] = make_int2(s.y, __float_as_int(dinv[s.y]));
        return;
    }

    // ---- gemm ----
    const int m = bid & 3;
    const float* x = (m == 0) ? x0 : (m == 1) ? x1 : (m == 2) ? x2 : x3;
    const unsigned short* Wg = wbf + (size_t)(m & 1) * 128 * 128;  // m=0,2->W1; 1,3->W2

    __shared__ unsigned short smem[128 * 136];  // Ws view (16384) / epilogue view (17408)

    const int n0   = (bid >> 2) * 128;
    const int w    = tid >> 6;       // 8 waves: rows w*16..w*16+15
    const int lane = tid & 63;
    const int am   = lane & 15;
    const int aq   = lane >> 4;
    const int r0   = w * 16;

    // A: direct global -> regs. Row clamped for OOB: garbage lands only in
    // C rows >= N, which are never stored.
    int arow = n0 + r0 + am; if (arow > N - 1) arow = N - 1;
    const float* xr = x + (size_t)arow * DD + aq * 8;
    float4 a0[4], a1[4];
#pragma unroll
    for (int q = 0; q < 4; ++q) {
        a0[q] = *(const float4*)(xr + q * 32);
        a1[q] = *(const float4*)(xr + q * 32 + 4);
    }

    // stage W: 16B copies with swizzle (uint4 index t -> t ^ ((t>>4)&7))
#pragma unroll
    for (int t = tid; t < 2048; t += 512)
        ((uint4*)smem)[t ^ ((t >> 4) & 7)] = ((const uint4*)Wg)[t];
    __syncthreads();

    // convert A to bf16 fragments (vmcnt wait lands here, after W staging)
    bf16x8 afr[4];
#pragma unroll
    for (int q = 0; q < 4; ++q) {
        afr[q][0] = (__bf16)a0[q].x; afr[q][1] = (__bf16)a0[q].y;
        afr[q][2] = (__bf16)a0[q].z; afr[q][3] = (__bf16)a0[q].w;
        afr[q][4] = (__bf16)a1[q].x; afr[q][5] = (__bf16)a1[q].y;
        afr[q][6] = (__bf16)a1[q].z; afr[q][7] = (__bf16)a1[q].w;
    }

    f32x4 acc[8] = {};
#pragma unroll
    for (int q = 0; q < 4; ++q) {
        const int kc = q * 32 + aq * 8;
#pragma unroll
        for (int ct = 0; ct < 8; ++ct) {
            bf16x8 bf = *(const bf16x8*)&smem[(ct * 16 + am) * 128 +
                                              (kc ^ ((am & 7) << 3))];
            acc[ct] = __builtin_amdgcn_mfma_f32_16x16x32_bf16(afr[q], bf, acc[ct], 0, 0, 0);
        }
    }
    __syncthreads();   // all waves done reading Ws view

    // single-pass epilogue into 128x136 view
    // C/D layout: col = lane&15, row = (lane>>4)*4 + i
    const int cc = lane & 15;
    const int rr = (lane >> 4) * 4;
#pragma unroll
    for (int ct = 0; ct < 8; ++ct)
#pragma unroll
        for (int i = 0; i < 4; ++i)
            smem[(r0 + rr + i) * 136 + ct * 16 + cc] = f2bf(acc[ct][i]);
    __syncthreads();

    // coalesced store into interleaved layout: h[(n*4 + m)*128 + c]; 4 x 16B per thread
#pragma unroll
    for (int k = 0; k < 4; ++k) {
        int f = k * 512 + tid;             // 128 rows x 16 chunks
        int row2 = f >> 4, ch = f & 15;
        int n = n0 + row2;
        if (n < N)
            *(uint4*)(h + ((size_t)n * 4 + m) * DD + ch * 8) =
                *(const uint4*)&smem[row2 * 136 + ch * 8];
    }
}

// ---------------- aggregation: gather by dst via CSR (interleaved bf16 h) -----
// ONE WAVE PER NODE (4 nodes/block): no barriers, no LDS.
// lane owns 16 B (8 cols of one matrix); one wave VMEM instr = full 1 KB h row.
// unroll 8 (deg~16 -> 2 batches) + ONE masked tail batch (clamped idx, zero wt).

static __device__ __forceinline__ void acc8(float* a, uint4 v, float wt) {
    a[0] += __uint_as_float(v.x << 16) * wt;
    a[1] += __uint_as_float(v.x & 0xffff0000u) * wt;
    a[2] += __uint_as_float(v.y << 16) * wt;
    a[3] += __uint_as_float(v.y & 0xffff0000u) * wt;
    a[4] += __uint_as_float(v.z << 16) * wt;
    a[5] += __uint_as_float(v.z & 0xffff0000u) * wt;
    a[6] += __uint_as_float(v.w << 16) * wt;
    a[7] += __uint_as_float(v.w & 0xffff0000u) * wt;
}

__global__ __launch_bounds__(256) void k_gather(
    const int* __restrict__ rp, const int2* __restrict__ csr,
    const float* __restrict__ dinv, const unsigned short* __restrict__ h,
    const float* __restrict__ b1, const float* __restrict__ b2,
    float* __restrict__ out, int N)
{
    const int n = blockIdx.x * 4 + (threadIdx.x >> 6);
    if (n >= N) return;
    const int lane = threadIdx.x & 63;
    const int m    = lane >> 4;          // matrix 0..3
    const int c    = (lane & 15) * 8;    // col base (8 floats)
    const size_t off = (size_t)lane * 8; // ushort offset within 512-wide node row

    const float dn = dinv[n];
    float a[8];

    // self-loop + bias
    {
        const float sn = dn * dn;
        const float* bb = (m & 1) ? b2 : b1;
        uint4 hv = *(const uint4*)(h + (size_t)n * 512 + off);
        float4 bv0 = *(const float4*)(bb + c);
        float4 bv1 = *(const float4*)(bb + c + 4);
        a[0] = bv0.x; a[1] = bv0.y; a[2] = bv0.z; a[3] = bv0.w;
        a[4] = bv1.x; a[5] = bv1.y; a[6] = bv1.z; a[7] = bv1.w;
        acc8(a, hv, sn);
    }

    int jb = rp[n];
    const int j1 = rp[n + 1];

    for (; jb + 7 < j1; jb += 8) {
        int2 e0 = csr[jb],     e1 = csr[jb + 1], e2 = csr[jb + 2], e3 = csr[jb + 3];
        int2 e4 = csr[jb + 4], e5 = csr[jb + 5], e6 = csr[jb + 6], e7 = csr[jb + 7];
        float w0 = __int_as_float(e0.y) * dn, w1 = __int_as_float(e1.y) * dn,
              w2 = __int_as_float(e2.y) * dn, w3 = __int_as_float(e3.y) * dn,
              w4 = __int_as_float(e4.y) * dn, w5 = __int_as_float(e5.y) * dn,
              w6 = __int_as_float(e6.y) * dn, w7 = __int_as_float(e7.y) * dn;
        uint4 v0 = *(const uint4*)(h + (size_t)e0.x * 512 + off);
        uint4 v1 = *(const uint4*)(h + (size_t)e1.x * 512 + off);
        uint4 v2 = *(const uint4*)(h + (size_t)e2.x * 512 + off);
        uint4 v3 = *(const uint4*)(h + (size_t)e3.x * 512 + off);
        uint4 v4 = *(const uint4*)(h + (size_t)e4.x * 512 + off);
        uint4 v5 = *(const uint4*)(h + (size_t)e5.x * 512 + off);
        uint4 v6 = *(const uint4*)(h + (size_t)e6.x * 512 + off);
        uint4 v7 = *(const uint4*)(h + (size_t)e7.x * 512 + off);
        acc8(a, v0, w0); acc8(a, v1, w1); acc8(a, v2, w2); acc8(a, v3, w3);
        acc8(a, v4, w4); acc8(a, v5, w5); acc8(a, v6, w6); acc8(a, v7, w7);
    }
    if (jb < j1) {               // one masked batch covers the remainder
        const int last = j1 - 1;
#pragma unroll
        for (int k = 0; k < 8; ++k) {
            int idx = jb + k;
            int2 e = csr[idx <= last ? idx : last];   // clamped: line is hot
            float wt = (idx <= last) ? __int_as_float(e.y) * dn : 0.f;
            uint4 v = *(const uint4*)(h + (size_t)e.x * 512 + off);
            acc8(a, v, wt);
        }
    }

    float* po = out + ((size_t)m * N + n) * DD + c;
    f32x4 r0, r1;
    r0.x = a[0]; r0.y = a[1]; r0.z = a[2]; r0.w = a[3];
    r1.x = a[4]; r1.y = a[5]; r1.z = a[6]; r1.w = a[7];
    // streaming store: out is never re-read -> keep L2/L3 for h gathers
    __builtin_nontemporal_store(r0, (f32x4*)po);
    __builtin_nontemporal_store(r1, (f32x4*)(po + 4));
}

// ---------------- launch ----------------

extern "C" void kernel_launch(void* const* d_in, const int* in_sizes, int n_in,
                              void* d_out, int out_size, void* d_ws, size_t ws_size,
                              hipStream_t stream) {
    const float* x0 = (const float*)d_in[0];
    const float* x1 = (const float*)d_in[1];
    const float* x2 = (const float*)d_in[2];
    const float* x3 = (const float*)d_in[3];
    const int*   ei = (const int*)d_in[4];
    const float* W1 = (const float*)d_in[5];
    const float* b1 = (const float*)d_in[6];
    const float* W2 = (const float*)d_in[7];
    const float* b2 = (const float*)d_in[8];
    float* out = (float*)d_out;

    const int N = in_sizes[0] / DD;   // 50000
    const int E = in_sizes[4] / 2;    // 800000

    // workspace layout
    int*   cnt  = (int*)d_ws;                        // 65536 ints
    int*   rp   = cnt + 65536;                       // 65536 (needs N+1)
    float* dinv = (float*)(rp + 65536);              // 65536
    int*   bsum = (int*)(dinv + 65536);              // 256
    unsigned short* wbf = (unsigned short*)(bsum + 256);  // 2*128*128 bf16 = 64 KB
    int2*  csr  = (int2*)(wbf + 2 * 128 * 128);      // E int2 {src, dinv[src]}
    unsigned short* h = (unsigned short*)(csr + E);  // interleaved [N][4][128] bf16 = 51.2 MB

    const int nscan = (N + 1023) / 1024;             // 49
    const int GB    = ((N + 127) / 128) * 4;         // gemm blocks = 1564
    const int FB    = (E / 2 + 511) / 512;           // fill blocks = 782

    hipMemsetAsync(cnt, 0, (size_t)N * sizeof(int), stream);
    k_front<<<8 + (E / 4 + 1023) / 1024, 1024, 0, stream>>>(ei + E, cnt, W1, W2, wbf, E);
    k_scan1<<<nscan, 1024, 0, stream>>>(cnt, rp, dinv, bsum, N);
    k_scan2<<<nscan, 1024, 0, stream>>>(bsum, rp, N);
    k_mid  <<<GB + FB, 512, 0, stream>>>(x0, x1, x2, x3, wbf, h,
                                         ei, rp, cnt, dinv, csr, N, E, GB);
    k_gather<<<(N + 3) / 4, 256, 0, stream>>>(rp, csr, dinv, h, b1, b2, out, N);
}

// Round 9
// 369.977 us; speedup vs baseline: 1.2813x; 1.0674x over previous
//
#include <hip/hip_runtime.h>

#define DD 128
#define PARTS 4
#define SLICES 16
#define PBINS 12544   // >= ceil(N/PARTS); N = 50000 -> 12500

typedef __bf16 bf16x8 __attribute__((ext_vector_type(8)));
typedef float f32x4 __attribute__((ext_vector_type(4)));

static __device__ __forceinline__ unsigned short f2bf(float f) {
    unsigned int u = __float_as_uint(f);
    u += 0x7FFF + ((u >> 16) & 1);   // round-to-nearest-even
    return (unsigned short)(u >> 16);
}

// ---------------- count: atomic-free partitioned LDS histogram ----------------
// blocks [0, PARTS*SLICES): block (p,c) reads edge-slice c, filters dst to
// partition p, LDS-atomic counts, writes partial[c][bin] coalesced (no global
// atomics anywhere). blocks >= PARTS*SLICES do the one-time W f32->bf16 convert.

__global__ __launch_bounds__(1024) void k_count(
    const int* __restrict__ dst, int* __restrict__ partial,
    const float* __restrict__ W1, const float* __restrict__ W2,
    unsigned short* __restrict__ wbf, int N, int E)
{
    const int bid = blockIdx.x;
    const int tid = threadIdx.x;
    if (bid >= PARTS * SLICES) {
        // W conversion: 8 blocks x 1024 threads x 1 float4 = 32768 elems (W1+W2)
        int i = (bid - PARTS * SLICES) * 1024 + tid;   // 0..8191
        float4 v = (i < 4096) ? ((const float4*)W1)[i] : ((const float4*)W2)[i - 4096];
        ushort4 b;
        b.x = f2bf(v.x); b.y = f2bf(v.y); b.z = f2bf(v.z); b.w = f2bf(v.w);
        *(ushort4*)&wbf[(size_t)i * 4] = b;
        return;
    }

    __shared__ int hist[PBINS];
    const int p     = bid & (PARTS - 1);
    const int c     = bid / PARTS;
    const int psize = (N + PARTS - 1) / PARTS;
    const int lo    = p * psize;

    for (int t = tid; t < psize; t += 1024) hist[t] = 0;
    __syncthreads();

    const int sl = (E + SLICES - 1) / SLICES;
    const int e0 = c * sl;
    const int e1 = (e0 + sl < E) ? e0 + sl : E;

    int e = e0 + tid * 4;
    for (; e + 3 < e1; e += 4096) {
        int4 d = *(const int4*)&dst[e];
        unsigned t0 = (unsigned)(d.x - lo), t1 = (unsigned)(d.y - lo);
        unsigned t2 = (unsigned)(d.z - lo), t3 = (unsigned)(d.w - lo);
        if (t0 < (unsigned)psize) atomicAdd(&hist[t0], 1);
        if (t1 < (unsigned)psize) atomicAdd(&hist[t1], 1);
        if (t2 < (unsigned)psize) atomicAdd(&hist[t2], 1);
        if (t3 < (unsigned)psize) atomicAdd(&hist[t3], 1);
    }
    if (e < e1) {                      // straddling tail (none when sl % 4 == 0)
        for (int k = e; k < e1; ++k) {
            unsigned t0 = (unsigned)(dst[k] - lo);
            if (t0 < (unsigned)psize) atomicAdd(&hist[t0], 1);
        }
    }
    __syncthreads();

    int* op = partial + (size_t)c * N;
    for (int t = tid; t < psize; t += 1024) {
        int g = lo + t;
        if (g < N) op[g] = hist[t];
    }
}

// ---------------- scan phase 1: sum slice-partials, block-local scan, dinv, cur ----

__global__ __launch_bounds__(1024) void k_scan1(const int* __restrict__ partial,
                                                int* __restrict__ rp,
                                                float* __restrict__ dinv,
                                                int* __restrict__ cur,
                                                int* __restrict__ bsum, int N) {
    __shared__ int wsum[16];
    const int tid = threadIdx.x, lane = tid & 63, wid = tid >> 6;
    const int i = blockIdx.x * 1024 + tid;
    int v = 0;
    if (i < N) {
#pragma unroll
        for (int c = 0; c < SLICES; ++c) v += partial[c * N + i];
    }
    int s = v;
    for (int off = 1; off < 64; off <<= 1) {
        int t = __shfl_up(s, off, 64);
        if (lane >= off) s += t;
    }
    if (lane == 63) wsum[wid] = s;
    __syncthreads();
    int woff = 0, total = 0;
#pragma unroll
    for (int w2 = 0; w2 < 16; ++w2) {
        int t = wsum[w2];
        if (w2 < wid) woff += t;
        total += t;
    }
    if (i < N) {
        rp[i + 1] = woff + s;                 // block-local inclusive
        dinv[i] = rsqrtf((float)(v + 1));     // +1 self-loop
        cur[i] = v;                           // fill cursor (consumed by atomicSub)
    }
    if (tid == 0) bsum[blockIdx.x] = total;
}

// scan phase 2: add exclusive prefix of block sums.
__global__ __launch_bounds__(1024) void k_scan2(const int* __restrict__ bsum,
                                                int* __restrict__ rp, int N) {
    __shared__ int boff_s;
    const int tid = threadIdx.x;
    if (tid < 64) {
        int v = (tid < (int)blockIdx.x) ? bsum[tid] : 0;   // nb <= 49 < 64
        for (int off = 32; off > 0; off >>= 1) v += __shfl_down(v, off, 64);
        if (tid == 0) boff_s = v;
    }
    __syncthreads();
    const int i = blockIdx.x * 1024 + tid;
    if (i < N) rp[i + 1] += boff_s;
    if (i == 0) rp[0] = 0;
}

// ---------------- mid: dense gemm (blocks [0, GB)) || CSR fill (blocks [GB, ...)) ----
// Fill is pure latency/atomic work; gemm is pure BW/MFMA work -> fill hides
// under gemm. The two are dataflow-independent (fill: rp/cur/dinv; gemm: wbf/x).

__global__ __launch_bounds__(512) void k_mid(
    const float* __restrict__ x0, const float* __restrict__ x1,
    const float* __restrict__ x2, const float* __restrict__ x3,
    const unsigned short* __restrict__ wbf,
    unsigned short* __restrict__ h,
    const int* __restrict__ ei, const int* __restrict__ rp,
    int* __restrict__ cur, const float* __restrict__ dinv,
    int2* __restrict__ csr,
    int N, int E, int GB)
{
    const int bid = blockIdx.x;
    const int tid = threadIdx.x;

    if (bid >= GB) {
        // ---- fill: consume cur as cursor via atomicSub; 2 edges/thread ----
        int e2 = ((bid - GB) * 512 + tid) * 2;
        if (e2 >= E) return;          // E % 2 == 0
        int2 s = *(const int2*)&ei[e2];
        int2 d = *(const int2*)&ei[E + e2];
        int o0 = atomicSub(&cur[d.x], 1);         // old in [1..deg]
        csr[rp[d.x] + o0 - 1] = make_int2(s.x, __float_as_int(dinv[s.x]));
        int o1 = atomicSub(&cur[d.y], 1);
        csr[rp[d.y] + o1 - 1] = make_int2(s.y, __float_as_int(dinv[s.y]));
        return;
    }

    // ---- gemm ----
    const int m = bid & 3;
    const float* x = (m == 0) ? x0 : (m == 1) ? x1 : (m == 2) ? x2 : x3;
    const unsigned short* Wg = wbf + (size_t)(m & 1) * 128 * 128;  // m=0,2->W1; 1,3->W2

    __shared__ unsigned short smem[128 * 136];  // Ws view (16384) / epilogue view (17408)

    const int n0   = (bid >> 2) * 128;
    const int w    = tid >> 6;       // 8 waves: rows w*16..w*16+15
    const int lane = tid & 63;
    const int am   = lane & 15;
    const int aq   = lane >> 4;
    const int r0   = w * 16;

    // A: direct global -> regs. Row clamped for OOB: garbage lands only in
    // C rows >= N, which are never stored.
    int arow = n0 + r0 + am; if (arow > N - 1) arow = N - 1;
    const float* xr = x + (size_t)arow * DD + aq * 8;
    float4 a0[4], a1[4];
#pragma unroll
    for (int q = 0; q < 4; ++q) {
        a0[q] = *(const float4*)(xr + q * 32);
        a1[q] = *(const float4*)(xr + q * 32 + 4);
    }

    // stage W: 16B copies with swizzle (uint4 index t -> t ^ ((t>>4)&7))
#pragma unroll
    for (int t = tid; t < 2048; t += 512)
        ((uint4*)smem)[t ^ ((t >> 4) & 7)] = ((const uint4*)Wg)[t];
    __syncthreads();

    // convert A to bf16 fragments (vmcnt wait lands here, after W staging)
    bf16x8 afr[4];
#pragma unroll
    for (int q = 0; q < 4; ++q) {
        afr[q][0] = (__bf16)a0[q].x; afr[q][1] = (__bf16)a0[q].y;
        afr[q][2] = (__bf16)a0[q].z; afr[q][3] = (__bf16)a0[q].w;
        afr[q][4] = (__bf16)a1[q].x; afr[q][5] = (__bf16)a1[q].y;
        afr[q][6] = (__bf16)a1[q].z; afr[q][7] = (__bf16)a1[q].w;
    }

    f32x4 acc[8] = {};
#pragma unroll
    for (int q = 0; q < 4; ++q) {
        const int kc = q * 32 + aq * 8;
#pragma unroll
        for (int ct = 0; ct < 8; ++ct) {
            bf16x8 bf = *(const bf16x8*)&smem[(ct * 16 + am) * 128 +
                                              (kc ^ ((am & 7) << 3))];
            acc[ct] = __builtin_amdgcn_mfma_f32_16x16x32_bf16(afr[q], bf, acc[ct], 0, 0, 0);
        }
    }
    __syncthreads();   // all waves done reading Ws view

    // single-pass epilogue into 128x136 view
    // C/D layout: col = lane&15, row = (lane>>4)*4 + i
    const int cc = lane & 15;
    const int rr = (lane >> 4) * 4;
#pragma unroll
    for (int ct = 0; ct < 8; ++ct)
#pragma unroll
        for (int i = 0; i < 4; ++i)
            smem[(r0 + rr + i) * 136 + ct * 16 + cc] = f2bf(acc[ct][i]);
    __syncthreads();

    // coalesced store into interleaved layout: h[(n*4 + m)*128 + c]; 4 x 16B per thread
#pragma unroll
    for (int k = 0; k < 4; ++k) {
        int f = k * 512 + tid;             // 128 rows x 16 chunks
        int row2 = f >> 4, ch = f & 15;
        int n = n0 + row2;
        if (n < N)
            *(uint4*)(h + ((size_t)n * 4 + m) * DD + ch * 8) =
                *(const uint4*)&smem[row2 * 136 + ch * 8];
    }
}

// ---------------- aggregation: gather by dst via CSR (interleaved bf16 h) -----
// ONE WAVE PER NODE (4 nodes/block): no barriers, no LDS.
// lane owns 16 B (8 cols of one matrix); one wave VMEM instr = full 1 KB h row.
// unroll 8 (deg~16 -> 2 batches) + ONE masked tail batch (clamped idx, zero wt).

static __device__ __forceinline__ void acc8(float* a, uint4 v, float wt) {
    a[0] += __uint_as_float(v.x << 16) * wt;
    a[1] += __uint_as_float(v.x & 0xffff0000u) * wt;
    a[2] += __uint_as_float(v.y << 16) * wt;
    a[3] += __uint_as_float(v.y & 0xffff0000u) * wt;
    a[4] += __uint_as_float(v.z << 16) * wt;
    a[5] += __uint_as_float(v.z & 0xffff0000u) * wt;
    a[6] += __uint_as_float(v.w << 16) * wt;
    a[7] += __uint_as_float(v.w & 0xffff0000u) * wt;
}

__global__ __launch_bounds__(256) void k_gather(
    const int* __restrict__ rp, const int2* __restrict__ csr,
    const float* __restrict__ dinv, const unsigned short* __restrict__ h,
    const float* __restrict__ b1, const float* __restrict__ b2,
    float* __restrict__ out, int N)
{
    const int n = blockIdx.x * 4 + (threadIdx.x >> 6);
    if (n >= N) return;
    const int lane = threadIdx.x & 63;
    const int m    = lane >> 4;          // matrix 0..3
    const int c    = (lane & 15) * 8;    // col base (8 floats)
    const size_t off = (size_t)lane * 8; // ushort offset within 512-wide node row

    const float dn = dinv[n];
    float a[8];

    // self-loop + bias
    {
        const float sn = dn * dn;
        const float* bb = (m & 1) ? b2 : b1;
        uint4 hv = *(const uint4*)(h + (size_t)n * 512 + off);
        float4 bv0 = *(const float4*)(bb + c);
        float4 bv1 = *(const float4*)(bb + c + 4);
        a[0] = bv0.x; a[1] = bv0.y; a[2] = bv0.z; a[3] = bv0.w;
        a[4] = bv1.x; a[5] = bv1.y; a[6] = bv1.z; a[7] = bv1.w;
        acc8(a, hv, sn);
    }

    int jb = rp[n];
    const int j1 = rp[n + 1];

    for (; jb + 7 < j1; jb += 8) {
        int2 e0 = csr[jb],     e1 = csr[jb + 1], e2 = csr[jb + 2], e3 = csr[jb + 3];
        int2 e4 = csr[jb + 4], e5 = csr[jb + 5], e6 = csr[jb + 6], e7 = csr[jb + 7];
        float w0 = __int_as_float(e0.y) * dn, w1 = __int_as_float(e1.y) * dn,
              w2 = __int_as_float(e2.y) * dn, w3 = __int_as_float(e3.y) * dn,
              w4 = __int_as_float(e4.y) * dn, w5 = __int_as_float(e5.y) * dn,
              w6 = __int_as_float(e6.y) * dn, w7 = __int_as_float(e7.y) * dn;
        uint4 v0 = *(const uint4*)(h + (size_t)e0.x * 512 + off);
        uint4 v1 = *(const uint4*)(h + (size_t)e1.x * 512 + off);
        uint4 v2 = *(const uint4*)(h + (size_t)e2.x * 512 + off);
        uint4 v3 = *(const uint4*)(h + (size_t)e3.x * 512 + off);
        uint4 v4 = *(const uint4*)(h + (size_t)e4.x * 512 + off);
        uint4 v5 = *(const uint4*)(h + (size_t)e5.x * 512 + off);
        uint4 v6 = *(const uint4*)(h + (size_t)e6.x * 512 + off);
        uint4 v7 = *(const uint4*)(h + (size_t)e7.x * 512 + off);
        acc8(a, v0, w0); acc8(a, v1, w1); acc8(a, v2, w2); acc8(a, v3, w3);
        acc8(a, v4, w4); acc8(a, v5, w5); acc8(a, v6, w6); acc8(a, v7, w7);
    }
    if (jb < j1) {               // one masked batch covers the remainder
        const int last = j1 - 1;
#pragma unroll
        for (int k = 0; k < 8; ++k) {
            int idx = jb + k;
            int2 e = csr[idx <= last ? idx : last];   // clamped: line is hot
            float wt = (idx <= last) ? __int_as_float(e.y) * dn : 0.f;
            uint4 v = *(const uint4*)(h + (size_t)e.x * 512 + off);
            acc8(a, v, wt);
        }
    }

    float* po = out + ((size_t)m * N + n) * DD + c;
    f32x4 r0, r1;
    r0.x = a[0]; r0.y = a[1]; r0.z = a[2]; r0.w = a[3];
    r1.x = a[4]; r1.y = a[5]; r1.z = a[6]; r1.w = a[7];
    // streaming store: out is never re-read -> keep L2/L3 for h gathers
    __builtin_nontemporal_store(r0, (f32x4*)po);
    __builtin_nontemporal_store(r1, (f32x4*)(po + 4));
}

// ---------------- launch ----------------

extern "C" void kernel_launch(void* const* d_in, const int* in_sizes, int n_in,
                              void* d_out, int out_size, void* d_ws, size_t ws_size,
                              hipStream_t stream) {
    const float* x0 = (const float*)d_in[0];
    const float* x1 = (const float*)d_in[1];
    const float* x2 = (const float*)d_in[2];
    const float* x3 = (const float*)d_in[3];
    const int*   ei = (const int*)d_in[4];
    const float* W1 = (const float*)d_in[5];
    const float* b1 = (const float*)d_in[6];
    const float* W2 = (const float*)d_in[7];
    const float* b2 = (const float*)d_in[8];
    float* out = (float*)d_out;

    const int N = in_sizes[0] / DD;   // 50000
    const int E = in_sizes[4] / 2;    // 800000

    // workspace layout
    int*   cur  = (int*)d_ws;                        // 65536 ints (fill cursor)
    int*   rp   = cur + 65536;                       // 65536 (needs N+1)
    float* dinv = (float*)(rp + 65536);              // 65536
    int*   bsum = (int*)(dinv + 65536);              // 256
    unsigned short* wbf = (unsigned short*)(bsum + 256);  // 2*128*128 bf16 = 64 KB
    int2*  csr  = (int2*)(wbf + 2 * 128 * 128);      // E int2 {src, dinv[src]}
    unsigned short* h = (unsigned short*)(csr + E);  // interleaved [N][4][128] bf16 = 51.2 MB

    // partial histograms overlay the csr region (SLICES*N ints = 3.2 MB <= 6.4 MB;
    // dead after k_scan1, before fill writes csr)
    int* partial = (int*)csr;

    const int nscan = (N + 1023) / 1024;             // 49
    const int GB    = ((N + 127) / 128) * 4;         // gemm blocks = 1564
    const int FB    = (E / 2 + 511) / 512;           // fill blocks = 782

    k_count<<<PARTS * SLICES + 8, 1024, 0, stream>>>(ei + E, partial, W1, W2, wbf, N, E);
    k_scan1<<<nscan, 1024, 0, stream>>>(partial, rp, dinv, cur, bsum, N);
    k_scan2<<<nscan, 1024, 0, stream>>>(bsum, rp, N);
    k_mid  <<<GB + FB, 512, 0, stream>>>(x0, x1, x2, x3, wbf, h,
                                         ei, rp, cur, dinv, csr, N, E, GB);
    k_gather<<<(N + 3) / 4, 256, 0, stream>>>(rp, csr, dinv, h, b1, b2, out, N);
}

// Round 10
// 366.665 us; speedup vs baseline: 1.2929x; 1.0090x over previous
//
#include <hip/hip_runtime.h>

#define DD 128
#define PARTS 8
#define SLICES 16
#define PBINS 6272    // >= ceil(N/PARTS) = 6250
#define FB (PARTS * SLICES)

typedef __bf16 bf16x8 __attribute__((ext_vector_type(8)));
typedef float f32x4 __attribute__((ext_vector_type(4)));

static __device__ __forceinline__ unsigned short f2bf(float f) {
    unsigned int u = __float_as_uint(f);
    u += 0x7FFF + ((u >> 16) & 1);   // round-to-nearest-even
    return (unsigned short)(u >> 16);
}

// ---------------- count: atomic-free partitioned LDS histogram ----------------
// block (p,c) reads edge-slice c, filters dst to partition p, LDS-atomic counts,
// writes partial[c][bin] coalesced. blocks >= FB do the one-time W f32->bf16.

__global__ __launch_bounds__(1024) void k_count(
    const int* __restrict__ dst, int* __restrict__ partial,
    const float* __restrict__ W1, const float* __restrict__ W2,
    unsigned short* __restrict__ wbf, int N, int E)
{
    const int bid = blockIdx.x;
    const int tid = threadIdx.x;
    if (bid >= FB) {
        // W conversion: 8 blocks x 1024 threads x 1 float4 = 32768 elems (W1+W2)
        int i = (bid - FB) * 1024 + tid;   // 0..8191
        float4 v = (i < 4096) ? ((const float4*)W1)[i] : ((const float4*)W2)[i - 4096];
        ushort4 b;
        b.x = f2bf(v.x); b.y = f2bf(v.y); b.z = f2bf(v.z); b.w = f2bf(v.w);
        *(ushort4*)&wbf[(size_t)i * 4] = b;
        return;
    }

    __shared__ int hist[PBINS];
    const int p     = bid & (PARTS - 1);
    const int c     = bid / PARTS;
    const int psize = (N + PARTS - 1) / PARTS;
    const int lo    = p * psize;

    for (int t = tid; t < psize; t += 1024) hist[t] = 0;
    __syncthreads();

    const int sl = (E + SLICES - 1) / SLICES;
    const int e0 = c * sl;
    const int e1 = (e0 + sl < E) ? e0 + sl : E;

    int e = e0 + tid * 4;
    for (; e + 3 < e1; e += 4096) {
        int4 d = *(const int4*)&dst[e];
        unsigned t0 = (unsigned)(d.x - lo), t1 = (unsigned)(d.y - lo);
        unsigned t2 = (unsigned)(d.z - lo), t3 = (unsigned)(d.w - lo);
        if (t0 < (unsigned)psize) atomicAdd(&hist[t0], 1);
        if (t1 < (unsigned)psize) atomicAdd(&hist[t1], 1);
        if (t2 < (unsigned)psize) atomicAdd(&hist[t2], 1);
        if (t3 < (unsigned)psize) atomicAdd(&hist[t3], 1);
    }
    if (e < e1) {                      // straddling tail (none when sl % 4 == 0)
        for (int k = e; k < e1; ++k) {
            unsigned t0 = (unsigned)(dst[k] - lo);
            if (t0 < (unsigned)psize) atomicAdd(&hist[t0], 1);
        }
    }
    __syncthreads();

    int* op = partial + (size_t)c * N;
    for (int t = tid; t < psize; t += 1024) {
        int g = lo + t;
        if (g < N) op[g] = hist[t];
    }
}

// ---------------- scan phase 1: slice-prefix (in place), block-local scan, dinv ----

__global__ __launch_bounds__(1024) void k_scan1(int* __restrict__ partial,
                                                int* __restrict__ rp,
                                                float* __restrict__ dinv,
                                                int* __restrict__ bsum, int N) {
    __shared__ int wsum[16];
    const int tid = threadIdx.x, lane = tid & 63, wid = tid >> 6;
    const int i = blockIdx.x * 1024 + tid;
    int v = 0;
    if (i < N) {
        int run = 0;
#pragma unroll
        for (int c = 0; c < SLICES; ++c) {
            int t = partial[(size_t)c * N + i];
            partial[(size_t)c * N + i] = run;   // exclusive prefix over slices
            run += t;
        }
        v = run;                                // total in-degree
    }
    int s = v;
    for (int off = 1; off < 64; off <<= 1) {
        int t = __shfl_up(s, off, 64);
        if (lane >= off) s += t;
    }
    if (lane == 63) wsum[wid] = s;
    __syncthreads();
    int woff = 0, total = 0;
#pragma unroll
    for (int w2 = 0; w2 < 16; ++w2) {
        int t = wsum[w2];
        if (w2 < wid) woff += t;
        total += t;
    }
    if (i < N) {
        rp[i + 1] = woff + s;                 // block-local inclusive
        dinv[i] = rsqrtf((float)(v + 1));     // +1 self-loop
    }
    if (tid == 0) bsum[blockIdx.x] = total;
}

// scan phase 2: add exclusive prefix of block sums.
__global__ __launch_bounds__(1024) void k_scan2(const int* __restrict__ bsum,
                                                int* __restrict__ rp, int N) {
    __shared__ int boff_s;
    const int tid = threadIdx.x;
    if (tid < 64) {
        int v = (tid < (int)blockIdx.x) ? bsum[tid] : 0;   // nb <= 49 < 64
        for (int off = 32; off > 0; off >>= 1) v += __shfl_down(v, off, 64);
        if (tid == 0) boff_s = v;
    }
    __syncthreads();
    const int i = blockIdx.x * 1024 + tid;
    if (i < N) rp[i + 1] += boff_s;
    if (i == 0) rp[0] = 0;
}

// ---------------- mid: CSR fill (blocks [0, FB), zero global atomics) || gemm ----
// fill block (p,c): LDS cursor = rp[g] + slice-prefix; stream slice edges; place
// owned edges via LDS atomicAdd -> disjoint csr ranges, race-free. Scheduled
// FIRST so its ~20us hides under the 1564 gemm blocks.

__global__ __launch_bounds__(512) void k_mid(
    const float* __restrict__ x0, const float* __restrict__ x1,
    const float* __restrict__ x2, const float* __restrict__ x3,
    const unsigned short* __restrict__ wbf,
    unsigned short* __restrict__ h,
    const int* __restrict__ ei, const int* __restrict__ rp,
    const float* __restrict__ dinv, const int* __restrict__ partial,
    int2* __restrict__ csr, int N, int E)
{
    __shared__ __align__(16) char smem_raw[128 * 136 * 2];  // 34816 B union
    const int bid = blockIdx.x;
    const int tid = threadIdx.x;

    if (bid < FB) {
        // ---- fill ----
        int* curs = (int*)smem_raw;           // PBINS*4 = 25088 B <= 34816
        const int p     = bid & (PARTS - 1);
        const int c     = bid / PARTS;
        const int psize = (N + PARTS - 1) / PARTS;
        const int lo    = p * psize;

        for (int t = tid; t < psize; t += 512) {
            int g = lo + t;
            curs[t] = (g < N) ? rp[g] + partial[(size_t)c * N + g] : 0;
        }
        __syncthreads();

        const int sl = (E + SLICES - 1) / SLICES;
        const int e0 = c * sl;
        const int e1 = (e0 + sl < E) ? e0 + sl : E;

        int e = e0 + tid * 4;
        for (; e + 3 < e1; e += 2048) {
            int4 d = *(const int4*)&ei[E + e];
            int4 s = *(const int4*)&ei[e];
            unsigned t0 = (unsigned)(d.x - lo), t1 = (unsigned)(d.y - lo);
            unsigned t2 = (unsigned)(d.z - lo), t3 = (unsigned)(d.w - lo);
            if (t0 < (unsigned)psize) {
                int pos = atomicAdd(&curs[t0], 1);
                csr[pos] = make_int2(s.x, __float_as_int(dinv[s.x]));
            }
            if (t1 < (unsigned)psize) {
                int pos = atomicAdd(&curs[t1], 1);
                csr[pos] = make_int2(s.y, __float_as_int(dinv[s.y]));
            }
            if (t2 < (unsigned)psize) {
                int pos = atomicAdd(&curs[t2], 1);
                csr[pos] = make_int2(s.z, __float_as_int(dinv[s.z]));
            }
            if (t3 < (unsigned)psize) {
                int pos = atomicAdd(&curs[t3], 1);
                csr[pos] = make_int2(s.w, __float_as_int(dinv[s.w]));
            }
        }
        if (e < e1) {                  // straddling tail (none when sl % 4 == 0)
            for (int k = e; k < e1; ++k) {
                int dk = ei[E + k];
                unsigned t0 = (unsigned)(dk - lo);
                if (t0 < (unsigned)psize) {
                    int sk = ei[k];
                    int pos = atomicAdd(&curs[t0], 1);
                    csr[pos] = make_int2(sk, __float_as_int(dinv[sk]));
                }
            }
        }
        return;
    }

    // ---- gemm ----
    const int gb = bid - FB;
    const int m  = gb & 3;
    const float* x = (m == 0) ? x0 : (m == 1) ? x1 : (m == 2) ? x2 : x3;
    const unsigned short* Wg = wbf + (size_t)(m & 1) * 128 * 128;  // m=0,2->W1; 1,3->W2
    unsigned short* smem = (unsigned short*)smem_raw;   // Ws view / epilogue view

    const int n0   = (gb >> 2) * 128;
    const int w    = tid >> 6;       // 8 waves: rows w*16..w*16+15
    const int lane = tid & 63;
    const int am   = lane & 15;
    const int aq   = lane >> 4;
    const int r0   = w * 16;

    // A: direct global -> regs. Row clamped for OOB: garbage lands only in
    // C rows >= N, which are never stored.
    int arow = n0 + r0 + am; if (arow > N - 1) arow = N - 1;
    const float* xr = x + (size_t)arow * DD + aq * 8;
    float4 a0[4], a1[4];
#pragma unroll
    for (int q = 0; q < 4; ++q) {
        a0[q] = *(const float4*)(xr + q * 32);
        a1[q] = *(const float4*)(xr + q * 32 + 4);
    }

    // stage W: 16B copies with swizzle (uint4 index t -> t ^ ((t>>4)&7))
#pragma unroll
    for (int t = tid; t < 2048; t += 512)
        ((uint4*)smem)[t ^ ((t >> 4) & 7)] = ((const uint4*)Wg)[t];
    __syncthreads();

    // convert A to bf16 fragments (vmcnt wait lands here, after W staging)
    bf16x8 afr[4];
#pragma unroll
    for (int q = 0; q < 4; ++q) {
        afr[q][0] = (__bf16)a0[q].x; afr[q][1] = (__bf16)a0[q].y;
        afr[q][2] = (__bf16)a0[q].z; afr[q][3] = (__bf16)a0[q].w;
        afr[q][4] = (__bf16)a1[q].x; afr[q][5] = (__bf16)a1[q].y;
        afr[q][6] = (__bf16)a1[q].z; afr[q][7] = (__bf16)a1[q].w;
    }

    f32x4 acc[8] = {};
#pragma unroll
    for (int q = 0; q < 4; ++q) {
        const int kc = q * 32 + aq * 8;
#pragma unroll
        for (int ct = 0; ct < 8; ++ct) {
            bf16x8 bf = *(const bf16x8*)&smem[(ct * 16 + am) * 128 +
                                              (kc ^ ((am & 7) << 3))];
            acc[ct] = __builtin_amdgcn_mfma_f32_16x16x32_bf16(afr[q], bf, acc[ct], 0, 0, 0);
        }
    }
    __syncthreads();   // all waves done reading Ws view

    // single-pass epilogue into 128x136 view
    // C/D layout: col = lane&15, row = (lane>>4)*4 + i
    const int cc = lane & 15;
    const int rr = (lane >> 4) * 4;
#pragma unroll
    for (int ct = 0; ct < 8; ++ct)
#pragma unroll
        for (int i = 0; i < 4; ++i)
            smem[(r0 + rr + i) * 136 + ct * 16 + cc] = f2bf(acc[ct][i]);
    __syncthreads();

    // coalesced store into interleaved layout: h[(n*4 + m)*128 + c]; 4 x 16B per thread
#pragma unroll
    for (int k = 0; k < 4; ++k) {
        int f = k * 512 + tid;             // 128 rows x 16 chunks
        int row2 = f >> 4, ch = f & 15;
        int n = n0 + row2;
        if (n < N)
            *(uint4*)(h + ((size_t)n * 4 + m) * DD + ch * 8) =
                *(const uint4*)&smem[row2 * 136 + ch * 8];
    }
}

// ---------------- aggregation: gather by dst via CSR (interleaved bf16 h) -----
// ONE WAVE PER NODE (4 nodes/block): no barriers, no LDS.
// lane owns 16 B (8 cols of one matrix); one wave VMEM instr = full 1 KB h row.
// unroll 8 (deg~16 -> 2 batches) + ONE masked tail batch (clamped idx, zero wt).

static __device__ __forceinline__ void acc8(float* a, uint4 v, float wt) {
    a[0] += __uint_as_float(v.x << 16) * wt;
    a[1] += __uint_as_float(v.x & 0xffff0000u) * wt;
    a[2] += __uint_as_float(v.y << 16) * wt;
    a[3] += __uint_as_float(v.y & 0xffff0000u) * wt;
    a[4] += __uint_as_float(v.z << 16) * wt;
    a[5] += __uint_as_float(v.z & 0xffff0000u) * wt;
    a[6] += __uint_as_float(v.w << 16) * wt;
    a[7] += __uint_as_float(v.w & 0xffff0000u) * wt;
}

__global__ __launch_bounds__(256) void k_gather(
    const int* __restrict__ rp, const int2* __restrict__ csr,
    const float* __restrict__ dinv, const unsigned short* __restrict__ h,
    const float* __restrict__ b1, const float* __restrict__ b2,
    float* __restrict__ out, int N)
{
    const int n = blockIdx.x * 4 + (threadIdx.x >> 6);
    if (n >= N) return;
    const int lane = threadIdx.x & 63;
    const int m    = lane >> 4;          // matrix 0..3
    const int c    = (lane & 15) * 8;    // col base (8 floats)
    const size_t off = (size_t)lane * 8; // ushort offset within 512-wide node row

    const float dn = dinv[n];
    float a[8];

    // self-loop + bias
    {
        const float sn = dn * dn;
        const float* bb = (m & 1) ? b2 : b1;
        uint4 hv = *(const uint4*)(h + (size_t)n * 512 + off);
        float4 bv0 = *(const float4*)(bb + c);
        float4 bv1 = *(const float4*)(bb + c + 4);
        a[0] = bv0.x; a[1] = bv0.y; a[2] = bv0.z; a[3] = bv0.w;
        a[4] = bv1.x; a[5] = bv1.y; a[6] = bv1.z; a[7] = bv1.w;
        acc8(a, hv, sn);
    }

    int jb = rp[n];
    const int j1 = rp[n + 1];

    for (; jb + 7 < j1; jb += 8) {
        int2 e0 = csr[jb],     e1 = csr[jb + 1], e2 = csr[jb + 2], e3 = csr[jb + 3];
        int2 e4 = csr[jb + 4], e5 = csr[jb + 5], e6 = csr[jb + 6], e7 = csr[jb + 7];
        float w0 = __int_as_float(e0.y) * dn, w1 = __int_as_float(e1.y) * dn,
              w2 = __int_as_float(e2.y) * dn, w3 = __int_as_float(e3.y) * dn,
              w4 = __int_as_float(e4.y) * dn, w5 = __int_as_float(e5.y) * dn,
              w6 = __int_as_float(e6.y) * dn, w7 = __int_as_float(e7.y) * dn;
        uint4 v0 = *(const uint4*)(h + (size_t)e0.x * 512 + off);
        uint4 v1 = *(const uint4*)(h + (size_t)e1.x * 512 + off);
        uint4 v2 = *(const uint4*)(h + (size_t)e2.x * 512 + off);
        uint4 v3 = *(const uint4*)(h + (size_t)e3.x * 512 + off);
        uint4 v4 = *(const uint4*)(h + (size_t)e4.x * 512 + off);
        uint4 v5 = *(const uint4*)(h + (size_t)e5.x * 512 + off);
        uint4 v6 = *(const uint4*)(h + (size_t)e6.x * 512 + off);
        uint4 v7 = *(const uint4*)(h + (size_t)e7.x * 512 + off);
        acc8(a, v0, w0); acc8(a, v1, w1); acc8(a, v2, w2); acc8(a, v3, w3);
        acc8(a, v4, w4); acc8(a, v5, w5); acc8(a, v6, w6); acc8(a, v7, w7);
    }
    if (jb < j1) {               // one masked batch covers the remainder
        const int last = j1 - 1;
#pragma unroll
        for (int k = 0; k < 8; ++k) {
            int idx = jb + k;
            int2 e = csr[idx <= last ? idx : last];   // clamped: line is hot
            float wt = (idx <= last) ? __int_as_float(e.y) * dn : 0.f;
            uint4 v = *(const uint4*)(h + (size_t)e.x * 512 + off);
            acc8(a, v, wt);
        }
    }

    float* po = out + ((size_t)m * N + n) * DD + c;
    f32x4 r0, r1;
    r0.x = a[0]; r0.y = a[1]; r0.z = a[2]; r0.w = a[3];
    r1.x = a[4]; r1.y = a[5]; r1.z = a[6]; r1.w = a[7];
    // streaming store: out is never re-read -> keep L2/L3 for h gathers
    __builtin_nontemporal_store(r0, (f32x4*)po);
    __builtin_nontemporal_store(r1, (f32x4*)(po + 4));
}

// ---------------- launch ----------------

extern "C" void kernel_launch(void* const* d_in, const int* in_sizes, int n_in,
                              void* d_out, int out_size, void* d_ws, size_t ws_size,
                              hipStream_t stream) {
    const float* x0 = (const float*)d_in[0];
    const float* x1 = (const float*)d_in[1];
    const float* x2 = (const float*)d_in[2];
    const float* x3 = (const float*)d_in[3];
    const int*   ei = (const int*)d_in[4];
    const float* W1 = (const float*)d_in[5];
    const float* b1 = (const float*)d_in[6];
    const float* W2 = (const float*)d_in[7];
    const float* b2 = (const float*)d_in[8];
    float* out = (float*)d_out;

    const int N = in_sizes[0] / DD;   // 50000
    const int E = in_sizes[4] / 2;    // 800000

    // workspace layout
    int*   rp   = (int*)d_ws;                        // 65536 (needs N+1)
    float* dinv = (float*)(rp + 65536);              // 65536
    int*   bsum = (int*)(dinv + 65536);              // 256
    unsigned short* wbf = (unsigned short*)(bsum + 256);  // 2*128*128 bf16 = 64 KB
    int2*  csr  = (int2*)(wbf + 2 * 128 * 128);      // E int2 {src, dinv[src]}
    unsigned short* h = (unsigned short*)(csr + E);  // interleaved [N][4][128] bf16 = 51.2 MB

    // slice-partial histograms live in d_out as scratch (SLICES*N ints = 3.2 MB
    // << out_size; dead before k_gather rewrites every byte of out)
    int* partial = (int*)d_out;

    const int nscan = (N + 1023) / 1024;             // 49
    const int GB    = ((N + 127) / 128) * 4;         // gemm blocks = 1564

    k_count<<<FB + 8, 1024, 0, stream>>>(ei + E, partial, W1, W2, wbf, N, E);
    k_scan1<<<nscan, 1024, 0, stream>>>(partial, rp, dinv, bsum, N);
    k_scan2<<<nscan, 1024, 0, stream>>>(bsum, rp, N);
    k_mid  <<<FB + GB, 512, 0, stream>>>(x0, x1, x2, x3, wbf, h,
                                         ei, rp, dinv, partial, csr, N, E);
    k_gather<<<(N + 3) / 4, 256, 0, stream>>>(rp, csr, dinv, h, b1, b2, out, N);
}